// Round 15
// baseline (869.904 us; speedup 1.0000x reference)
//
#include <hip/hip_runtime.h>
#include <hip/hip_bf16.h>

typedef unsigned short u16;
typedef unsigned int   u32;
typedef __attribute__((ext_vector_type(8))) short short8;
typedef __attribute__((ext_vector_type(4))) float f32x4;

__device__ __forceinline__ u16 f2bf(float f) {
  u32 u = __float_as_uint(f);
  u += 0x7FFFu + ((u >> 16) & 1u);   // RNE
  return (u16)(u >> 16);
}
__device__ __forceinline__ float bf2f(u16 h) { return __uint_as_float(((u32)h) << 16); }
// HW packed conversion: v_cvt_pk_bf16_f32 (RNE)
__device__ __forceinline__ u32 pk2(float lo, float hi) {
  union { __hip_bfloat162 h; u32 u; } c;
  c.h = __float22bfloat162_rn(make_float2(lo, hi));
  return c.u;
}
__device__ __forceinline__ float lo16f(u32 u) { return __uint_as_float(u << 16); }
__device__ __forceinline__ float hi16f(u32 u) { return __uint_as_float(u & 0xffff0000u); }
__device__ __forceinline__ float lrelu(float v) { return v > 0.f ? v : 0.01f * v; }

// Channel permutation (verified round 3): physical output position c'=32s+16a+4g+q
// holds logical channel sig(c'). Packed bf16 MFMA outputs fed directly as
// next-layer B-fragments arrive in LOGICAL k-order -> next-layer weights
// permuted only on the output (m) dimension.
__host__ __device__ __forceinline__ int sig(int c) {
  return ((c >> 5) << 5) | ((c & 12) << 1) | (((c >> 4) & 1) << 2) | (c & 3);
}

union U8 { u32 w[4]; short8 v; };

#define MFMA16(A, B, C) __builtin_amdgcn_mfma_f32_16x16x32_bf16(A, B, C, 0, 0, 0)

// wcat chunk bases (short8 units): w1 [0,2048), w2 [2048,6144), w3 [6144,7168).
#define W2_BASE 2048
#define W3_BASE 6144

// msg record layout: position p = 16g + 8h + j holds channel ch = 32h + 8g + j.

// ------------- edge MLP: ZERO LDS — all weights streamed from L2 with rolling
// register prefetch; 256-thread blocks for multi-block/CU co-scheduling
// (r9-r13: 512-thr blocks pin at 1 block/CU; node_agg's 256-thr blocks hit 45%).
__global__ __launch_bounds__(256, 4) void edge_mlp(
    const float* __restrict__ x, const int* __restrict__ src, const int* __restrict__ dst,
    const short8* __restrict__ wcat,
    const float* __restrict__ b1p, const float* __restrict__ b2p, const float* __restrict__ b3p,
    const float* __restrict__ w4p, const float* __restrict__ b4,
    const int* __restrict__ rowptr, const int* __restrict__ ord,
    u16* __restrict__ msgbuf, float* __restrict__ eout, int E)
{
  const int tid  = threadIdx.x;
  const int lane = tid & 63;
  const int wv   = tid >> 6;         // 0..3
  const int g    = lane >> 4;        // k-group
  const int r    = lane & 15;        // edge slot / weight row slot
  const int eb   = (blockIdx.x * 4 + wv) * 32;
  const int e0   = eb + r, e1 = eb + 16 + r;
  const int ec0  = e0 < E ? e0 : E - 1;
  const int ec1  = e1 < E ? e1 : E - 1;
  const int sn0 = src[ec0], dn0 = dst[ec0];
  const int sn1 = src[ec1], dn1 = dst[ec1];
  const float b4v = b4[0];

  // ---- issue gather + CSR-slot loads FIRST ----
  const float* xsr0 = x + (size_t)sn0 * 64 + 8 * g;
  const float* xdr0 = x + (size_t)dn0 * 64 + 8 * g;
  const float* xsr1 = x + (size_t)sn1 * 64 + 8 * g;
  const float* xdr1 = x + (size_t)dn1 * 64 + 8 * g;
  const float4 a0s0 = *(const float4*)(xsr0),      a0s1 = *(const float4*)(xsr0 + 4);
  const float4 a0s2 = *(const float4*)(xsr0 + 32), a0s3 = *(const float4*)(xsr0 + 36);
  const float4 a0d0 = *(const float4*)(xdr0),      a0d1 = *(const float4*)(xdr0 + 4);
  const float4 a0d2 = *(const float4*)(xdr0 + 32), a0d3 = *(const float4*)(xdr0 + 36);
  const float4 a1s0 = *(const float4*)(xsr1),      a1s1 = *(const float4*)(xsr1 + 4);
  const float4 a1s2 = *(const float4*)(xsr1 + 32), a1s3 = *(const float4*)(xsr1 + 36);
  const float4 a1d0 = *(const float4*)(xdr1),      a1d1 = *(const float4*)(xdr1 + 4);
  const float4 a1d2 = *(const float4*)(xdr1 + 32), a1d3 = *(const float4*)(xdr1 + 36);
  const int pos0 = rowptr[dn0] + ord[ec0];   // no atomic (r14)
  const int pos1 = rowptr[dn1] + ord[ec1];

  // ---- prefetch w1 tile 0 (L2-resident) ----
  short8 w1f0 = wcat[lane];
  short8 w1f1 = wcat[64 + lane];

  // ---- pack B-fragments: d = x[src]-x[dst]; x[src] kept as bf16 for msg ----
  U8 bA0, bB0, bA1, bB1, sA0lo, sA0hi, sA1lo, sA1hi;
  bA0.w[0] = pk2(a0s0.x - a0d0.x, a0s0.y - a0d0.y);
  bA0.w[1] = pk2(a0s0.z - a0d0.z, a0s0.w - a0d0.w);
  bA0.w[2] = pk2(a0s1.x - a0d1.x, a0s1.y - a0d1.y);
  bA0.w[3] = pk2(a0s1.z - a0d1.z, a0s1.w - a0d1.w);
  bB0.w[0] = pk2(a0s2.x - a0d2.x, a0s2.y - a0d2.y);
  bB0.w[1] = pk2(a0s2.z - a0d2.z, a0s2.w - a0d2.w);
  bB0.w[2] = pk2(a0s3.x - a0d3.x, a0s3.y - a0d3.y);
  bB0.w[3] = pk2(a0s3.z - a0d3.z, a0s3.w - a0d3.w);
  bA1.w[0] = pk2(a1s0.x - a1d0.x, a1s0.y - a1d0.y);
  bA1.w[1] = pk2(a1s0.z - a1d0.z, a1s0.w - a1d0.w);
  bA1.w[2] = pk2(a1s1.x - a1d1.x, a1s1.y - a1d1.y);
  bA1.w[3] = pk2(a1s1.z - a1d1.z, a1s1.w - a1d1.w);
  bB1.w[0] = pk2(a1s2.x - a1d2.x, a1s2.y - a1d2.y);
  bB1.w[1] = pk2(a1s2.z - a1d2.z, a1s2.w - a1d2.w);
  bB1.w[2] = pk2(a1s3.x - a1d3.x, a1s3.y - a1d3.y);
  bB1.w[3] = pk2(a1s3.z - a1d3.z, a1s3.w - a1d3.w);
  sA0lo.w[0] = pk2(a0s0.x, a0s0.y); sA0lo.w[1] = pk2(a0s0.z, a0s0.w);
  sA0lo.w[2] = pk2(a0s1.x, a0s1.y); sA0lo.w[3] = pk2(a0s1.z, a0s1.w);
  sA0hi.w[0] = pk2(a0s2.x, a0s2.y); sA0hi.w[1] = pk2(a0s2.z, a0s2.w);
  sA0hi.w[2] = pk2(a0s3.x, a0s3.y); sA0hi.w[3] = pk2(a0s3.z, a0s3.w);
  sA1lo.w[0] = pk2(a1s0.x, a1s0.y); sA1lo.w[1] = pk2(a1s0.z, a1s0.w);
  sA1lo.w[2] = pk2(a1s1.x, a1s1.y); sA1lo.w[3] = pk2(a1s1.z, a1s1.w);
  sA1hi.w[0] = pk2(a1s2.x, a1s2.y); sA1hi.w[1] = pk2(a1s2.z, a1s2.w);
  sA1hi.w[2] = pk2(a1s3.x, a1s3.y); sA1hi.w[3] = pk2(a1s3.z, a1s3.w);

  // ---- layer 1: 256 <- 64; w1 streamed, rolling depth-1 tile prefetch ----
  U8 h1A[8], h1B[8];   // MFMA-quad layout (r14): word w=2t+j -> h1A[w>>2].w[w&3]
  {
    const float* b1l = b1p + 4 * g;
#pragma unroll
    for (int t = 0; t < 16; t++) {
      short8 a0 = w1f0, a1 = w1f1;
      if (t < 15) {
        w1f0 = wcat[(2 * t + 2) * 64 + lane];
        w1f1 = wcat[(2 * t + 3) * 64 + lane];
      }
      f32x4 p = {}, q = {};
      p = MFMA16(a0, bA0.v, p); p = MFMA16(a1, bB0.v, p);
      q = MFMA16(a0, bA1.v, q); q = MFMA16(a1, bB1.v, q);
      float4 bb = *(const float4*)(b1l + 16 * t);
      const int w0 = 2 * t, w1 = 2 * t + 1;
      h1A[w0 >> 2].w[w0 & 3] = pk2(lrelu(p[0] + bb.x), lrelu(p[1] + bb.y));
      h1A[w1 >> 2].w[w1 & 3] = pk2(lrelu(p[2] + bb.z), lrelu(p[3] + bb.w));
      h1B[w0 >> 2].w[w0 & 3] = pk2(lrelu(q[0] + bb.x), lrelu(q[1] + bb.y));
      h1B[w1 >> 2].w[w1 & 3] = pk2(lrelu(q[2] + bb.z), lrelu(q[3] + bb.w));
    }
  }

  // ---- layer 2: 128 <- 256; w2 streamed, rolling in-place prefetch ----
  // frag s of tile t+1 loads right after tile t consumes slot s (~7 MFMA-pairs
  // of cover); x4 waves/SIMD TLP multiplies the hiding.
  U8 h2A[4], h2B[4];
  {
    short8 w2f[8];
#pragma unroll
    for (int s = 0; s < 8; s++) w2f[s] = wcat[W2_BASE + s * 64 + lane];
    const float* b2l = b2p + 4 * g;
#pragma unroll
    for (int t = 0; t < 8; t++) {
      f32x4 p = {}, q = {};
#pragma unroll
      for (int s = 0; s < 8; s++) {
        short8 a = w2f[s];
        if (t < 7) w2f[s] = wcat[W2_BASE + ((t + 1) * 8 + s) * 64 + lane];
        p = MFMA16(a, h1A[s].v, p);
        q = MFMA16(a, h1B[s].v, q);
      }
      float4 bb = *(const float4*)(b2l + 16 * t);
      const int w0 = 2 * t, w1 = 2 * t + 1;
      h2A[w0 >> 2].w[w0 & 3] = pk2(lrelu(p[0] + bb.x), lrelu(p[1] + bb.y));
      h2A[w1 >> 2].w[w1 & 3] = pk2(lrelu(p[2] + bb.z), lrelu(p[3] + bb.w));
      h2B[w0 >> 2].w[w0 & 3] = pk2(lrelu(q[0] + bb.x), lrelu(q[1] + bb.y));
      h2B[w1 >> 2].w[w1 & 3] = pk2(lrelu(q[2] + bb.z), lrelu(q[3] + bb.w));
    }
  }

  // ---- layer 3 + layer 4 fused; w3 streamed, rolling in-place prefetch ----
  float dot0 = 0.f, dot1 = 0.f;
  {
    short8 w3f[4];
#pragma unroll
    for (int s = 0; s < 4; s++) w3f[s] = wcat[W3_BASE + s * 64 + lane];
    const float* b3l = b3p + 4 * g;
    const float* w4l = w4p + 4 * g;
#pragma unroll
    for (int t = 0; t < 4; t++) {
      f32x4 p = {}, q = {};
#pragma unroll
      for (int s = 0; s < 4; s++) {
        short8 a = w3f[s];
        if (t < 3) w3f[s] = wcat[W3_BASE + ((t + 1) * 4 + s) * 64 + lane];
        p = MFMA16(a, h2A[s].v, p);
        q = MFMA16(a, h2B[s].v, q);
      }
      float4 bb = *(const float4*)(b3l + 16 * t);
      float4 ww = *(const float4*)(w4l + 16 * t);
      dot0 += lrelu(p[0] + bb.x) * ww.x + lrelu(p[1] + bb.y) * ww.y
            + lrelu(p[2] + bb.z) * ww.z + lrelu(p[3] + bb.w) * ww.w;
      dot1 += lrelu(q[0] + bb.x) * ww.x + lrelu(q[1] + bb.y) * ww.y
            + lrelu(q[2] + bb.z) * ww.z + lrelu(q[3] + bb.w) * ww.w;
    }
  }
  dot0 += __shfl_xor(dot0, 16); dot0 += __shfl_xor(dot0, 32);
  dot1 += __shfl_xor(dot1, 16); dot1 += __shfl_xor(dot1, 32);
  const float ev0 = 1.f / (1.f + __expf(-(dot0 + b4v)));
  const float ev1 = 1.f / (1.f + __expf(-(dot1 + b4v)));

  // ---- outputs: no atomic, no shfl — pos known since kernel start ----
  if (g == 0) {
    if (e0 < E) eout[e0] = ev0;
    if (e1 < E) eout[e1] = ev1;
  }
  if (e0 < E) {
    u16* mp = msgbuf + (size_t)pos0 * 64 + g * 16;
    U8 m;
    m.w[0] = pk2(ev0 * lo16f(sA0lo.w[0]), ev0 * hi16f(sA0lo.w[0]));
    m.w[1] = pk2(ev0 * lo16f(sA0lo.w[1]), ev0 * hi16f(sA0lo.w[1]));
    m.w[2] = pk2(ev0 * lo16f(sA0lo.w[2]), ev0 * hi16f(sA0lo.w[2]));
    m.w[3] = pk2(ev0 * lo16f(sA0lo.w[3]), ev0 * hi16f(sA0lo.w[3]));
    *(short8*)(mp) = m.v;
    m.w[0] = pk2(ev0 * lo16f(sA0hi.w[0]), ev0 * hi16f(sA0hi.w[0]));
    m.w[1] = pk2(ev0 * lo16f(sA0hi.w[1]), ev0 * hi16f(sA0hi.w[1]));
    m.w[2] = pk2(ev0 * lo16f(sA0hi.w[2]), ev0 * hi16f(sA0hi.w[2]));
    m.w[3] = pk2(ev0 * lo16f(sA0hi.w[3]), ev0 * hi16f(sA0hi.w[3]));
    *(short8*)(mp + 8) = m.v;
  }
  if (e1 < E) {
    u16* mp = msgbuf + (size_t)pos1 * 64 + g * 16;
    U8 m;
    m.w[0] = pk2(ev1 * lo16f(sA1lo.w[0]), ev1 * hi16f(sA1lo.w[0]));
    m.w[1] = pk2(ev1 * lo16f(sA1lo.w[1]), ev1 * hi16f(sA1lo.w[1]));
    m.w[2] = pk2(ev1 * lo16f(sA1lo.w[2]), ev1 * hi16f(sA1lo.w[2]));
    m.w[3] = pk2(ev1 * lo16f(sA1lo.w[3]), ev1 * hi16f(sA1lo.w[3]));
    *(short8*)(mp) = m.v;
    m.w[0] = pk2(ev1 * lo16f(sA1hi.w[0]), ev1 * hi16f(sA1hi.w[0]));
    m.w[1] = pk2(ev1 * lo16f(sA1hi.w[1]), ev1 * hi16f(sA1hi.w[1]));
    m.w[2] = pk2(ev1 * lo16f(sA1hi.w[2]), ev1 * hi16f(sA1hi.w[2]));
    m.w[3] = pk2(ev1 * lo16f(sA1hi.w[3]), ev1 * hi16f(sA1hi.w[3]));
    *(short8*)(mp + 8) = m.v;
  }
}

// -------- degree histogram + CSR slot assignment (ord = slot within bin) -----
__global__ void deg_hist(const int* __restrict__ dst, int* __restrict__ degi,
                         int* __restrict__ ord, int E)
{
  const int i = blockIdx.x * 256 + threadIdx.x;
  if (i < E) ord[i] = atomicAdd(&degi[dst[i]], 1);
}

// ---------------- CSR build: exclusive scan of degi ----------------
__global__ void scan_part(const int* __restrict__ degi, int* __restrict__ rowptr,
                          int* __restrict__ bsum, int N)
{
  __shared__ int wsum[4];
  const int tid = threadIdx.x, lane = tid & 63, w = tid >> 6;
  const int base = blockIdx.x * 1024 + tid * 4;
  int d0 = 0, d1 = 0, d2 = 0, d3 = 0;
  if (base + 3 < N) {
    int4 v = *(const int4*)(degi + base);
    d0 = v.x; d1 = v.y; d2 = v.z; d3 = v.w;
  } else {
    if (base < N)     d0 = degi[base];
    if (base + 1 < N) d1 = degi[base + 1];
    if (base + 2 < N) d2 = degi[base + 2];
    if (base + 3 < N) d3 = degi[base + 3];
  }
  const int ts = d0 + d1 + d2 + d3;
  int sc = ts;
#pragma unroll
  for (int o = 1; o < 64; o <<= 1) { int v = __shfl_up(sc, o); if (lane >= o) sc += v; }
  if (lane == 63) wsum[w] = sc;
  __syncthreads();
  int woff = 0;
  for (int i = 0; i < w; i++) woff += wsum[i];
  const int ex = woff + sc - ts;
  if (base < N)     rowptr[base]     = ex;
  if (base + 1 < N) rowptr[base + 1] = ex + d0;
  if (base + 2 < N) rowptr[base + 2] = ex + d0 + d1;
  if (base + 3 < N) rowptr[base + 3] = ex + d0 + d1 + d2;
  if (tid == 255) bsum[blockIdx.x] = woff + sc;
}

__global__ void scan_bsum(int* __restrict__ bsum, int nb)  // nb <= 256
{
  __shared__ int wsum[4];
  const int tid = threadIdx.x, lane = tid & 63, w = tid >> 6;
  const int v = tid < nb ? bsum[tid] : 0;
  int sc = v;
#pragma unroll
  for (int o = 1; o < 64; o <<= 1) { int t = __shfl_up(sc, o); if (lane >= o) sc += t; }
  if (lane == 63) wsum[w] = sc;
  __syncthreads();
  int woff = 0;
  for (int i = 0; i < w; i++) woff += wsum[i];
  if (tid < nb) bsum[tid] = woff + sc - v;
}

__global__ void scan_add(int* __restrict__ rowptr, const int* __restrict__ bsum,
                         int N, int E)
{
  const int base = blockIdx.x * 1024 + threadIdx.x * 4;
  const int off = bsum[blockIdx.x];
#pragma unroll
  for (int i = 0; i < 4; i++)
    if (base + i < N) rowptr[base + i] += off;
  if (blockIdx.x == 0 && threadIdx.x == 0) rowptr[N] = E;
}

// -------- aggregate + finalize on MFMA: 16 nodes/wave, 4 waves/block --------
__global__ __launch_bounds__(256, 4) void node_agg_mfma(
    const float* __restrict__ x, const u16* __restrict__ msgbuf,
    const int* __restrict__ rowptr, const short8* __restrict__ wfin,
    const float* __restrict__ bias, float* __restrict__ A, int N)
{
  __shared__ short8 ldsW[1024];        // 16 KiB: [w_self|w_neigh] fragment-linear
  __shared__ float  nbuf[4][16][68];   // 17.4 KiB: per-wave node means (padded)
  const int tid = threadIdx.x, wv = tid >> 6, lane = tid & 63;
  const int g = lane >> 4, r = lane & 15;
  for (int i = tid; i < 1024; i += 256) ldsW[i] = wfin[i];

  const int n0 = (blockIdx.x * 4 + wv) * 16;
  const int nr = (n0 + r) < N ? (n0 + r) : N - 1;
  const float* xp = x + (size_t)nr * 64 + 8 * g;
  const float4 xf0 = *(const float4*)(xp);
  const float4 xf1 = *(const float4*)(xp + 4);
  const float4 xf2 = *(const float4*)(xp + 32);
  const float4 xf3 = *(const float4*)(xp + 36);
  int rp = 0;
  if (lane < 17) rp = rowptr[min(n0 + lane, N)];
  const int cch = (((lane >> 3) & 1) << 5) | ((lane >> 4) << 3) | (lane & 7);
  for (int rr = 0; rr < 16; rr++) {
    const int s = __shfl(rp, rr);
    const int t = __shfl(rp, rr + 1);
    float acc = 0.f;
    for (int j = s; j < t; j += 4) {
      const int j1 = (j + 1 < t) ? j + 1 : j;
      const int j2 = (j + 2 < t) ? j + 2 : j;
      const int j3 = (j + 3 < t) ? j + 3 : j;
      const float v0 = bf2f(msgbuf[(size_t)j  * 64 + lane]);
      const float v1 = bf2f(msgbuf[(size_t)j1 * 64 + lane]);
      const float v2 = bf2f(msgbuf[(size_t)j2 * 64 + lane]);
      const float v3 = bf2f(msgbuf[(size_t)j3 * 64 + lane]);
      const float m1 = (j + 1 < t) ? 1.f : 0.f;
      const float m2 = (j + 2 < t) ? 1.f : 0.f;
      const float m3 = (j + 3 < t) ? 1.f : 0.f;
      acc += v0 + m1 * v1 + m2 * v2 + m3 * v3;
    }
    const float inv = 1.f / fmaxf((float)(t - s), 1.f);
    nbuf[wv][rr][cch] = acc * inv;   // logical channel order
  }
  __syncthreads();   // covers ldsW staging (nbuf is per-wave)

  U8 bf0, bf1, bf2q, bf3q;
  bf0.w[0] = pk2(xf0.x, xf0.y); bf0.w[1] = pk2(xf0.z, xf0.w);
  bf0.w[2] = pk2(xf1.x, xf1.y); bf0.w[3] = pk2(xf1.z, xf1.w);
  bf1.w[0] = pk2(xf2.x, xf2.y); bf1.w[1] = pk2(xf2.z, xf2.w);
  bf1.w[2] = pk2(xf3.x, xf3.y); bf1.w[3] = pk2(xf3.z, xf3.w);
  {
    const float* nb = nbuf[wv][r];
    const float4 n0v = *(const float4*)(nb + 8 * g);
    const float4 n1v = *(const float4*)(nb + 8 * g + 4);
    const float4 n2v = *(const float4*)(nb + 32 + 8 * g);
    const float4 n3v = *(const float4*)(nb + 32 + 8 * g + 4);
    bf2q.w[0] = pk2(n0v.x, n0v.y); bf2q.w[1] = pk2(n0v.z, n0v.w);
    bf2q.w[2] = pk2(n1v.x, n1v.y); bf2q.w[3] = pk2(n1v.z, n1v.w);
    bf3q.w[0] = pk2(n2v.x, n2v.y); bf3q.w[1] = pk2(n2v.z, n2v.w);
    bf3q.w[2] = pk2(n3v.x, n3v.y); bf3q.w[3] = pk2(n3v.z, n3v.w);
  }

  f32x4 acct[4] = {};
#pragma unroll
  for (int t = 0; t < 4; t++) {
    acct[t] = MFMA16(ldsW[(t * 4 + 0) * 64 + lane], bf0.v,  acct[t]);
    acct[t] = MFMA16(ldsW[(t * 4 + 1) * 64 + lane], bf1.v,  acct[t]);
    acct[t] = MFMA16(ldsW[(t * 4 + 2) * 64 + lane], bf2q.v, acct[t]);
    acct[t] = MFMA16(ldsW[(t * 4 + 3) * 64 + lane], bf3q.v, acct[t]);
  }

  f32x4 av[4];
  float ss = 0.f;
#pragma unroll
  for (int t = 0; t < 4; t++) {
    const float4 bb = *(const float4*)(bias + 16 * t + 4 * g);
    av[t][0] = lrelu(acct[t][0] + bb.x);
    av[t][1] = lrelu(acct[t][1] + bb.y);
    av[t][2] = lrelu(acct[t][2] + bb.z);
    av[t][3] = lrelu(acct[t][3] + bb.w);
    ss += av[t][0] * av[t][0] + av[t][1] * av[t][1]
        + av[t][2] * av[t][2] + av[t][3] * av[t][3];
  }
  ss += __shfl_xor(ss, 16); ss += __shfl_xor(ss, 32);
  const float rn = 1.f / fmaxf(sqrtf(ss), 1e-12f);
  if (n0 + r < N) {
    float* ap = A + (size_t)(n0 + r) * 64 + 4 * g;
#pragma unroll
    for (int t = 0; t < 4; t++) {
      float4 o;
      o.x = av[t][0] * rn; o.y = av[t][1] * rn;
      o.z = av[t][2] * rn; o.w = av[t][3] * rn;
      *(float4*)(ap + 16 * t) = o;
    }
  }
}

// --------- weight conversion: fragment-linear chunk layouts ----
__global__ void convert_w(const float* __restrict__ w1, const float* __restrict__ w2,
                          const float* __restrict__ w3,
                          const float* __restrict__ b1, const float* __restrict__ b2,
                          const float* __restrict__ b3, const float* __restrict__ w4,
                          const float* __restrict__ w_self, const float* __restrict__ w_neigh,
                          u16* __restrict__ wcat, u16* __restrict__ wfin,
                          float* __restrict__ b1p, float* __restrict__ b2p,
                          float* __restrict__ b3p, float* __restrict__ w4p)
{
  const int idx = blockIdx.x * 256 + threadIdx.x;
  if (idx < 57344) {
    const float* w; int K, nsteps, loc;
    if (idx < 16384)      { loc = idx;         w = w1; K = 64;  nsteps = 2; }
    else if (idx < 49152) { loc = idx - 16384; w = w2; K = 256; nsteps = 8; }
    else                  { loc = idx - 49152; w = w3; K = 128; nsteps = 4; }
    const int chunk = loc >> 9;
    const int lane  = (loc >> 3) & 63;
    const int j     = loc & 7;
    const int t = chunk / nsteps, s = chunk % nsteps;
    const int m = sig(t * 16 + (lane & 15));
    const int k = s * 32 + (lane >> 4) * 8 + j;
    wcat[idx] = f2bf(w[m * K + k]);
  } else if (idx < 65536) {
    // wfin: [w_self | w_neigh] as 64x128, chunk c = t*4+s, NO permutation
    const int o = idx - 57344;
    const int c = o >> 9, lane = (o >> 3) & 63, j = o & 7;
    const int t = c >> 2, s = c & 3;
    const int m = 16 * t + (lane & 15);
    const int k = 32 * s + ((lane >> 4) << 3) + j;
    wfin[o] = f2bf(k < 64 ? w_self[m * 64 + k] : w_neigh[m * 64 + (k - 64)]);
  }
  if (idx < 256) b1p[idx] = b1[sig(idx)];
  if (idx < 128) b2p[idx] = b2[sig(idx)];
  if (idx < 64)  { b3p[idx] = b3[sig(idx)]; w4p[idx] = w4[sig(idx)]; }
}

extern "C" void kernel_launch(void* const* d_in, const int* in_sizes, int n_in,
                              void* d_out, int out_size, void* d_ws, size_t ws_size,
                              hipStream_t stream)
{
  const float* x       = (const float*)d_in[0];
  const int*   src     = (const int*)d_in[1];
  const int*   dst     = (const int*)d_in[2];
  const float* w1      = (const float*)d_in[3];
  const float* b1      = (const float*)d_in[4];
  const float* w2      = (const float*)d_in[5];
  const float* b2      = (const float*)d_in[6];
  const float* w3      = (const float*)d_in[7];
  const float* b3      = (const float*)d_in[8];
  const float* w4      = (const float*)d_in[9];
  const float* b4      = (const float*)d_in[10];
  const float* w_self  = (const float*)d_in[11];
  const float* w_neigh = (const float*)d_in[12];
  const float* bias    = (const float*)d_in[13];

  const int N = in_sizes[0] / 64;
  const int E = in_sizes[1];

  float* A    = (float*)d_out;                    // [N,64]
  float* eout = (float*)d_out + (size_t)N * 64;   // [E]

  char* ws = (char*)d_ws;
  size_t off = 0;
  auto alloc = [&](size_t bytes) {
    void* p = ws + off;
    off = (off + bytes + 255) & ~(size_t)255;
    return p;
  };
  int*    degi   = (int*)alloc((size_t)N * 4);
  int*    rowptr = (int*)alloc((size_t)(N + 1) * 4);
  int*    ord    = (int*)alloc((size_t)E * 4);
  int*    bsum   = (int*)alloc(1024 * 4);
  short8* wcat   = (short8*)alloc((size_t)57344 * 2);
  short8* wfin   = (short8*)alloc((size_t)8192 * 2);
  float*  b1p    = (float*)alloc(256 * 4);
  float*  b2p    = (float*)alloc(128 * 4);
  float*  b3p    = (float*)alloc(64 * 4);
  float*  w4p    = (float*)alloc(64 * 4);
  u16*    msgbuf = (u16*)alloc((size_t)E * 128);

  hipMemsetAsync(degi, 0, (size_t)N * sizeof(int), stream);

  convert_w<<<256, 256, 0, stream>>>(w1, w2, w3, b1, b2, b3, w4, w_self, w_neigh,
                                     (u16*)wcat, (u16*)wfin, b1p, b2p, b3p, w4p);

  deg_hist<<<(E + 255) / 256, 256, 0, stream>>>(dst, degi, ord, E);

  const int nsb = (N + 1023) / 1024;   // <= 256 for N <= 262144
  scan_part<<<nsb, 256, 0, stream>>>(degi, rowptr, bsum, N);
  scan_bsum<<<1, 256, 0, stream>>>(bsum, nsb);
  scan_add<<<nsb, 256, 0, stream>>>(rowptr, bsum, N, E);

  const int nblk = (E + 127) / 128;    // 128 edges per 256-thread block
  edge_mlp<<<nblk, 256, 0, stream>>>(x, src, dst, wcat, b1p, b2p, b3p, w4p, b4,
                                     rowptr, ord, msgbuf, eout, E);

  const int nblk2 = (N + 63) / 64;     // 64 nodes per 256-thread block
  node_agg_mfma<<<nblk2, 256, 0, stream>>>(x, msgbuf, rowptr, wfin, bias, A, N);
}

// Round 16
// 305.274 us; speedup vs baseline: 2.8496x; 2.8496x over previous
//
#include <hip/hip_runtime.h>
#include <hip/hip_bf16.h>

typedef unsigned short u16;
typedef unsigned int   u32;
typedef __attribute__((ext_vector_type(8))) short short8;
typedef __attribute__((ext_vector_type(4))) float f32x4;

__device__ __forceinline__ u16 f2bf(float f) {
  u32 u = __float_as_uint(f);
  u += 0x7FFFu + ((u >> 16) & 1u);   // RNE
  return (u16)(u >> 16);
}
__device__ __forceinline__ float bf2f(u16 h) { return __uint_as_float(((u32)h) << 16); }
// HW packed conversion: v_cvt_pk_bf16_f32 (RNE)
__device__ __forceinline__ u32 pk2(float lo, float hi) {
  union { __hip_bfloat162 h; u32 u; } c;
  c.h = __float22bfloat162_rn(make_float2(lo, hi));
  return c.u;
}
__device__ __forceinline__ float lrelu(float v) { return v > 0.f ? v : 0.01f * v; }

// Channel permutation (verified round 3): physical output position c'=32s+16a+4g+q
// holds logical channel sig(c'). Packed bf16 MFMA outputs fed directly as
// next-layer B-fragments arrive in LOGICAL k-order -> next-layer weights
// permuted only on the output (m) dimension.
__host__ __device__ __forceinline__ int sig(int c) {
  return ((c >> 5) << 5) | ((c & 12) << 1) | (((c >> 4) & 1) << 2) | (c & 3);
}

union U8 { u32 w[4]; short8 v; };

#define MFMA16(A, B, C) __builtin_amdgcn_mfma_f32_16x16x32_bf16(A, B, C, 0, 0, 0)

// LDS chunk bases in short8 units: w1 [0,2048), w2 [2048,6144), w3 [6144,7168)
#define W2_BASE 2048
#define W3_BASE 6144
#define NCHUNK8 7168   // 114688 bytes total

// msg record layout: position p = 16g + 8h + j holds channel ch = 32h + 8g + j.

// ------------- edge MLP: full-LDS weights, 64 edges/wave (4 B-sets) ----------
// (512,2)-family is the only no-spill config (r10/r11/r15: every other
// launch_bounds -> 64-VGPR cap -> catastrophic spill). (512,1) raises the cap
// to >=256 for the 4-set state (~225 peak). Occupancy stays 8 waves/CU —
// proven non-binding (r9-r13); per-wave amortization is the lever.
__global__ __launch_bounds__(512, 1) void edge_mlp(
    const float* __restrict__ x, const int* __restrict__ src, const int* __restrict__ dst,
    const short8* __restrict__ wcat,
    const float* __restrict__ b1p, const float* __restrict__ b2p, const float* __restrict__ b3p,
    const float* __restrict__ w4p, const float* __restrict__ b4,
    const int* __restrict__ rowptr, const int* __restrict__ ord,
    u16* __restrict__ msgbuf, float* __restrict__ eout, int E)
{
  __shared__ short8 ldsw[NCHUNK8];   // 112 KiB
  const int tid  = threadIdx.x;
  const int lane = tid & 63;
  const int wv   = tid >> 6;         // 0..7
  const int g    = lane >> 4;        // k-group
  const int r    = lane & 15;        // edge slot / weight row slot
  const int eb   = (blockIdx.x * 8 + wv) * 64;
  const float b4v = b4[0];

  int e[4], ec[4], sn[4], dn[4], pos[4];
#pragma unroll
  for (int c = 0; c < 4; c++) {
    e[c]  = eb + 16 * c + r;
    ec[c] = e[c] < E ? e[c] : E - 1;
    sn[c] = src[ec[c]];
    dn[c] = dst[ec[c]];
  }

  // ---- issue gather + CSR-slot loads FIRST (latency hides under staging) ----
  float4 xs[4][4], xd[4][4];
#pragma unroll
  for (int c = 0; c < 4; c++) {
    const float* xsr = x + (size_t)sn[c] * 64 + 8 * g;
    const float* xdr = x + (size_t)dn[c] * 64 + 8 * g;
    xs[c][0] = *(const float4*)(xsr);      xs[c][1] = *(const float4*)(xsr + 4);
    xs[c][2] = *(const float4*)(xsr + 32); xs[c][3] = *(const float4*)(xsr + 36);
    xd[c][0] = *(const float4*)(xdr);      xd[c][1] = *(const float4*)(xdr + 4);
    xd[c][2] = *(const float4*)(xdr + 32); xd[c][3] = *(const float4*)(xdr + 36);
  }
#pragma unroll
  for (int c = 0; c < 4; c++) pos[c] = rowptr[dn[c]] + ord[ec[c]];

  // ---- stage ALL weights via direct global->LDS DMA ----
  {
    const short8* gp = wcat + wv * 64 + lane;
    short8*       lp = ldsw + wv * 64;
#pragma unroll
    for (int i = 0; i < 14; i++) {
      __builtin_amdgcn_global_load_lds(
          (const __attribute__((address_space(1))) u32*)(gp + i * 512),
          (__attribute__((address_space(3))) u32*)(lp + i * 512), 16, 0, 0);
    }
  }
  __syncthreads();

  // ---- pack B-fragments: d = x[src]-x[dst] (x regs released after pack) ----
  U8 bA[4], bB[4];
#pragma unroll
  for (int c = 0; c < 4; c++) {
    bA[c].w[0] = pk2(xs[c][0].x - xd[c][0].x, xs[c][0].y - xd[c][0].y);
    bA[c].w[1] = pk2(xs[c][0].z - xd[c][0].z, xs[c][0].w - xd[c][0].w);
    bA[c].w[2] = pk2(xs[c][1].x - xd[c][1].x, xs[c][1].y - xd[c][1].y);
    bA[c].w[3] = pk2(xs[c][1].z - xd[c][1].z, xs[c][1].w - xd[c][1].w);
    bB[c].w[0] = pk2(xs[c][2].x - xd[c][2].x, xs[c][2].y - xd[c][2].y);
    bB[c].w[1] = pk2(xs[c][2].z - xd[c][2].z, xs[c][2].w - xd[c][2].w);
    bB[c].w[2] = pk2(xs[c][3].x - xd[c][3].x, xs[c][3].y - xd[c][3].y);
    bB[c].w[3] = pk2(xs[c][3].z - xd[c][3].z, xs[c][3].w - xd[c][3].w);
  }

  // ---- layer 1: 256 <- 64; each weight read feeds 4 independent MFMA ----
  U8 h1[4][8];   // MFMA-quad layout: word w=2t+j -> h1[c][w>>2].w[w&3]
  {
    const float* b1l = b1p + 4 * g;
#pragma unroll
    for (int t = 0; t < 16; t++) {
      short8 a0 = ldsw[(t * 2 + 0) * 64 + lane];
      short8 a1 = ldsw[(t * 2 + 1) * 64 + lane];
      float4 bb = *(const float4*)(b1l + 16 * t);
      const int w0 = 2 * t, w1 = 2 * t + 1;
#pragma unroll
      for (int c = 0; c < 4; c++) {
        f32x4 p = {};
        p = MFMA16(a0, bA[c].v, p);
        p = MFMA16(a1, bB[c].v, p);
        h1[c][w0 >> 2].w[w0 & 3] = pk2(lrelu(p[0] + bb.x), lrelu(p[1] + bb.y));
        h1[c][w1 >> 2].w[w1 & 3] = pk2(lrelu(p[2] + bb.z), lrelu(p[3] + bb.w));
      }
    }
  }

  // ---- layer 2: 128 <- 256 ----
  U8 h2[4][4];
  {
    const float* b2l = b2p + 4 * g;
#pragma unroll
    for (int t = 0; t < 8; t++) {
      f32x4 p0 = {}, p1 = {}, p2 = {}, p3 = {};
#pragma unroll
      for (int s = 0; s < 8; s++) {
        short8 a = ldsw[W2_BASE + (t * 8 + s) * 64 + lane];
        p0 = MFMA16(a, h1[0][s].v, p0);
        p1 = MFMA16(a, h1[1][s].v, p1);
        p2 = MFMA16(a, h1[2][s].v, p2);
        p3 = MFMA16(a, h1[3][s].v, p3);
      }
      float4 bb = *(const float4*)(b2l + 16 * t);
      const int w0 = 2 * t, w1 = 2 * t + 1;
      h2[0][w0 >> 2].w[w0 & 3] = pk2(lrelu(p0[0] + bb.x), lrelu(p0[1] + bb.y));
      h2[0][w1 >> 2].w[w1 & 3] = pk2(lrelu(p0[2] + bb.z), lrelu(p0[3] + bb.w));
      h2[1][w0 >> 2].w[w0 & 3] = pk2(lrelu(p1[0] + bb.x), lrelu(p1[1] + bb.y));
      h2[1][w1 >> 2].w[w1 & 3] = pk2(lrelu(p1[2] + bb.z), lrelu(p1[3] + bb.w));
      h2[2][w0 >> 2].w[w0 & 3] = pk2(lrelu(p2[0] + bb.x), lrelu(p2[1] + bb.y));
      h2[2][w1 >> 2].w[w1 & 3] = pk2(lrelu(p2[2] + bb.z), lrelu(p2[3] + bb.w));
      h2[3][w0 >> 2].w[w0 & 3] = pk2(lrelu(p3[0] + bb.x), lrelu(p3[1] + bb.y));
      h2[3][w1 >> 2].w[w1 & 3] = pk2(lrelu(p3[2] + bb.z), lrelu(p3[3] + bb.w));
    }
  }

  // ---- layer 3 + layer 4 fused ----
  float dot[4] = {0.f, 0.f, 0.f, 0.f};
  {
    const float* b3l = b3p + 4 * g;
    const float* w4l = w4p + 4 * g;
#pragma unroll
    for (int t = 0; t < 4; t++) {
      f32x4 p0 = {}, p1 = {}, p2 = {}, p3 = {};
#pragma unroll
      for (int s = 0; s < 4; s++) {
        short8 a = ldsw[W3_BASE + (t * 4 + s) * 64 + lane];
        p0 = MFMA16(a, h2[0][s].v, p0);
        p1 = MFMA16(a, h2[1][s].v, p1);
        p2 = MFMA16(a, h2[2][s].v, p2);
        p3 = MFMA16(a, h2[3][s].v, p3);
      }
      float4 bb = *(const float4*)(b3l + 16 * t);
      float4 ww = *(const float4*)(w4l + 16 * t);
      dot[0] += lrelu(p0[0] + bb.x) * ww.x + lrelu(p0[1] + bb.y) * ww.y
              + lrelu(p0[2] + bb.z) * ww.z + lrelu(p0[3] + bb.w) * ww.w;
      dot[1] += lrelu(p1[0] + bb.x) * ww.x + lrelu(p1[1] + bb.y) * ww.y
              + lrelu(p1[2] + bb.z) * ww.z + lrelu(p1[3] + bb.w) * ww.w;
      dot[2] += lrelu(p2[0] + bb.x) * ww.x + lrelu(p2[1] + bb.y) * ww.y
              + lrelu(p2[2] + bb.z) * ww.z + lrelu(p2[3] + bb.w) * ww.w;
      dot[3] += lrelu(p3[0] + bb.x) * ww.x + lrelu(p3[1] + bb.y) * ww.y
              + lrelu(p3[2] + bb.z) * ww.z + lrelu(p3[3] + bb.w) * ww.w;
    }
  }
  float ev[4];
#pragma unroll
  for (int c = 0; c < 4; c++) {
    float d = dot[c];
    d += __shfl_xor(d, 16);
    d += __shfl_xor(d, 32);
    ev[c] = 1.f / (1.f + __expf(-(d + b4v)));
  }

  // ---- outputs: eout + msg records; x[src] reloaded (L2-hot lines) ----
  if (g == 0) {
#pragma unroll
    for (int c = 0; c < 4; c++)
      if (e[c] < E) eout[e[c]] = ev[c];
  }
#pragma unroll
  for (int c = 0; c < 4; c++) {
    if (e[c] < E) {
      const float* xsr = x + (size_t)sn[c] * 64 + 8 * g;
      const float4 v0 = *(const float4*)(xsr);
      const float4 v1 = *(const float4*)(xsr + 4);
      const float4 v2 = *(const float4*)(xsr + 32);
      const float4 v3 = *(const float4*)(xsr + 36);
      u16* mp = msgbuf + (size_t)pos[c] * 64 + g * 16;
      U8 m;
      m.w[0] = pk2(ev[c] * v0.x, ev[c] * v0.y);
      m.w[1] = pk2(ev[c] * v0.z, ev[c] * v0.w);
      m.w[2] = pk2(ev[c] * v1.x, ev[c] * v1.y);
      m.w[3] = pk2(ev[c] * v1.z, ev[c] * v1.w);
      *(short8*)(mp) = m.v;
      m.w[0] = pk2(ev[c] * v2.x, ev[c] * v2.y);
      m.w[1] = pk2(ev[c] * v2.z, ev[c] * v2.w);
      m.w[2] = pk2(ev[c] * v3.x, ev[c] * v3.y);
      m.w[3] = pk2(ev[c] * v3.z, ev[c] * v3.w);
      *(short8*)(mp + 8) = m.v;
    }
  }
}

// -------- degree histogram + CSR slot assignment (ord = slot within bin) -----
__global__ void deg_hist(const int* __restrict__ dst, int* __restrict__ degi,
                         int* __restrict__ ord, int E)
{
  const int i = blockIdx.x * 256 + threadIdx.x;
  if (i < E) ord[i] = atomicAdd(&degi[dst[i]], 1);
}

// ---------------- CSR build: exclusive scan of degi ----------------
__global__ void scan_part(const int* __restrict__ degi, int* __restrict__ rowptr,
                          int* __restrict__ bsum, int N)
{
  __shared__ int wsum[4];
  const int tid = threadIdx.x, lane = tid & 63, w = tid >> 6;
  const int base = blockIdx.x * 1024 + tid * 4;
  int d0 = 0, d1 = 0, d2 = 0, d3 = 0;
  if (base + 3 < N) {
    int4 v = *(const int4*)(degi + base);
    d0 = v.x; d1 = v.y; d2 = v.z; d3 = v.w;
  } else {
    if (base < N)     d0 = degi[base];
    if (base + 1 < N) d1 = degi[base + 1];
    if (base + 2 < N) d2 = degi[base + 2];
    if (base + 3 < N) d3 = degi[base + 3];
  }
  const int ts = d0 + d1 + d2 + d3;
  int sc = ts;
#pragma unroll
  for (int o = 1; o < 64; o <<= 1) { int v = __shfl_up(sc, o); if (lane >= o) sc += v; }
  if (lane == 63) wsum[w] = sc;
  __syncthreads();
  int woff = 0;
  for (int i = 0; i < w; i++) woff += wsum[i];
  const int ex = woff + sc - ts;
  if (base < N)     rowptr[base]     = ex;
  if (base + 1 < N) rowptr[base + 1] = ex + d0;
  if (base + 2 < N) rowptr[base + 2] = ex + d0 + d1;
  if (base + 3 < N) rowptr[base + 3] = ex + d0 + d1 + d2;
  if (tid == 255) bsum[blockIdx.x] = woff + sc;
}

__global__ void scan_bsum(int* __restrict__ bsum, int nb)  // nb <= 256
{
  __shared__ int wsum[4];
  const int tid = threadIdx.x, lane = tid & 63, w = tid >> 6;
  const int v = tid < nb ? bsum[tid] : 0;
  int sc = v;
#pragma unroll
  for (int o = 1; o < 64; o <<= 1) { int t = __shfl_up(sc, o); if (lane >= o) sc += t; }
  if (lane == 63) wsum[w] = sc;
  __syncthreads();
  int woff = 0;
  for (int i = 0; i < w; i++) woff += wsum[i];
  if (tid < nb) bsum[tid] = woff + sc - v;
}

__global__ void scan_add(int* __restrict__ rowptr, const int* __restrict__ bsum,
                         int N, int E)
{
  const int base = blockIdx.x * 1024 + threadIdx.x * 4;
  const int off = bsum[blockIdx.x];
#pragma unroll
  for (int i = 0; i < 4; i++)
    if (base + i < N) rowptr[base + i] += off;
  if (blockIdx.x == 0 && threadIdx.x == 0) rowptr[N] = E;
}

// -------- aggregate + finalize on MFMA: 16 nodes/wave, 4 waves/block --------
__global__ __launch_bounds__(256, 4) void node_agg_mfma(
    const float* __restrict__ x, const u16* __restrict__ msgbuf,
    const int* __restrict__ rowptr, const short8* __restrict__ wfin,
    const float* __restrict__ bias, float* __restrict__ A, int N)
{
  __shared__ short8 ldsW[1024];        // 16 KiB: [w_self|w_neigh] fragment-linear
  __shared__ float  nbuf[4][16][68];   // 17.4 KiB: per-wave node means (padded)
  const int tid = threadIdx.x, wv = tid >> 6, lane = tid & 63;
  const int g = lane >> 4, r = lane & 15;
  for (int i = tid; i < 1024; i += 256) ldsW[i] = wfin[i];

  const int n0 = (blockIdx.x * 4 + wv) * 16;
  const int nr = (n0 + r) < N ? (n0 + r) : N - 1;
  const float* xp = x + (size_t)nr * 64 + 8 * g;
  const float4 xf0 = *(const float4*)(xp);
  const float4 xf1 = *(const float4*)(xp + 4);
  const float4 xf2 = *(const float4*)(xp + 32);
  const float4 xf3 = *(const float4*)(xp + 36);
  int rp = 0;
  if (lane < 17) rp = rowptr[min(n0 + lane, N)];
  const int cch = (((lane >> 3) & 1) << 5) | ((lane >> 4) << 3) | (lane & 7);
  for (int rr = 0; rr < 16; rr++) {
    const int s = __shfl(rp, rr);
    const int t = __shfl(rp, rr + 1);
    float acc = 0.f;
    for (int j = s; j < t; j += 4) {
      const int j1 = (j + 1 < t) ? j + 1 : j;
      const int j2 = (j + 2 < t) ? j + 2 : j;
      const int j3 = (j + 3 < t) ? j + 3 : j;
      const float v0 = bf2f(msgbuf[(size_t)j  * 64 + lane]);
      const float v1 = bf2f(msgbuf[(size_t)j1 * 64 + lane]);
      const float v2 = bf2f(msgbuf[(size_t)j2 * 64 + lane]);
      const float v3 = bf2f(msgbuf[(size_t)j3 * 64 + lane]);
      const float m1 = (j + 1 < t) ? 1.f : 0.f;
      const float m2 = (j + 2 < t) ? 1.f : 0.f;
      const float m3 = (j + 3 < t) ? 1.f : 0.f;
      acc += v0 + m1 * v1 + m2 * v2 + m3 * v3;
    }
    const float inv = 1.f / fmaxf((float)(t - s), 1.f);
    nbuf[wv][rr][cch] = acc * inv;   // logical channel order
  }
  __syncthreads();   // covers ldsW staging (nbuf is per-wave)

  U8 bf0, bf1, bf2q, bf3q;
  bf0.w[0] = pk2(xf0.x, xf0.y); bf0.w[1] = pk2(xf0.z, xf0.w);
  bf0.w[2] = pk2(xf1.x, xf1.y); bf0.w[3] = pk2(xf1.z, xf1.w);
  bf1.w[0] = pk2(xf2.x, xf2.y); bf1.w[1] = pk2(xf2.z, xf2.w);
  bf1.w[2] = pk2(xf3.x, xf3.y); bf1.w[3] = pk2(xf3.z, xf3.w);
  {
    const float* nb = nbuf[wv][r];
    const float4 n0v = *(const float4*)(nb + 8 * g);
    const float4 n1v = *(const float4*)(nb + 8 * g + 4);
    const float4 n2v = *(const float4*)(nb + 32 + 8 * g);
    const float4 n3v = *(const float4*)(nb + 32 + 8 * g + 4);
    bf2q.w[0] = pk2(n0v.x, n0v.y); bf2q.w[1] = pk2(n0v.z, n0v.w);
    bf2q.w[2] = pk2(n1v.x, n1v.y); bf2q.w[3] = pk2(n1v.z, n1v.w);
    bf3q.w[0] = pk2(n2v.x, n2v.y); bf3q.w[1] = pk2(n2v.z, n2v.w);
    bf3q.w[2] = pk2(n3v.x, n3v.y); bf3q.w[3] = pk2(n3v.z, n3v.w);
  }

  f32x4 acct[4] = {};
#pragma unroll
  for (int t = 0; t < 4; t++) {
    acct[t] = MFMA16(ldsW[(t * 4 + 0) * 64 + lane], bf0.v,  acct[t]);
    acct[t] = MFMA16(ldsW[(t * 4 + 1) * 64 + lane], bf1.v,  acct[t]);
    acct[t] = MFMA16(ldsW[(t * 4 + 2) * 64 + lane], bf2q.v, acct[t]);
    acct[t] = MFMA16(ldsW[(t * 4 + 3) * 64 + lane], bf3q.v, acct[t]);
  }

  f32x4 av[4];
  float ss = 0.f;
#pragma unroll
  for (int t = 0; t < 4; t++) {
    const float4 bb = *(const float4*)(bias + 16 * t + 4 * g);
    av[t][0] = lrelu(acct[t][0] + bb.x);
    av[t][1] = lrelu(acct[t][1] + bb.y);
    av[t][2] = lrelu(acct[t][2] + bb.z);
    av[t][3] = lrelu(acct[t][3] + bb.w);
    ss += av[t][0] * av[t][0] + av[t][1] * av[t][1]
        + av[t][2] * av[t][2] + av[t][3] * av[t][3];
  }
  ss += __shfl_xor(ss, 16); ss += __shfl_xor(ss, 32);
  const float rn = 1.f / fmaxf(sqrtf(ss), 1e-12f);
  if (n0 + r < N) {
    float* ap = A + (size_t)(n0 + r) * 64 + 4 * g;
#pragma unroll
    for (int t = 0; t < 4; t++) {
      float4 o;
      o.x = av[t][0] * rn; o.y = av[t][1] * rn;
      o.z = av[t][2] * rn; o.w = av[t][3] * rn;
      *(float4*)(ap + 16 * t) = o;
    }
  }
}

// --------- weight conversion: fragment-linear chunk layouts ----
__global__ void convert_w(const float* __restrict__ w1, const float* __restrict__ w2,
                          const float* __restrict__ w3,
                          const float* __restrict__ b1, const float* __restrict__ b2,
                          const float* __restrict__ b3, const float* __restrict__ w4,
                          const float* __restrict__ w_self, const float* __restrict__ w_neigh,
                          u16* __restrict__ wcat, u16* __restrict__ wfin,
                          float* __restrict__ b1p, float* __restrict__ b2p,
                          float* __restrict__ b3p, float* __restrict__ w4p)
{
  const int idx = blockIdx.x * 256 + threadIdx.x;
  if (idx < 57344) {
    const float* w; int K, nsteps, loc;
    if (idx < 16384)      { loc = idx;         w = w1; K = 64;  nsteps = 2; }
    else if (idx < 49152) { loc = idx - 16384; w = w2; K = 256; nsteps = 8; }
    else                  { loc = idx - 49152; w = w3; K = 128; nsteps = 4; }
    const int chunk = loc >> 9;
    const int lane  = (loc >> 3) & 63;
    const int j     = loc & 7;
    const int t = chunk / nsteps, s = chunk % nsteps;
    const int m = sig(t * 16 + (lane & 15));
    const int k = s * 32 + (lane >> 4) * 8 + j;
    wcat[idx] = f2bf(w[m * K + k]);
  } else if (idx < 65536) {
    // wfin: [w_self | w_neigh] as 64x128, chunk c = t*4+s, NO permutation
    const int o = idx - 57344;
    const int c = o >> 9, lane = (o >> 3) & 63, j = o & 7;
    const int t = c >> 2, s = c & 3;
    const int m = 16 * t + (lane & 15);
    const int k = 32 * s + ((lane >> 4) << 3) + j;
    wfin[o] = f2bf(k < 64 ? w_self[m * 64 + k] : w_neigh[m * 64 + (k - 64)]);
  }
  if (idx < 256) b1p[idx] = b1[sig(idx)];
  if (idx < 128) b2p[idx] = b2[sig(idx)];
  if (idx < 64)  { b3p[idx] = b3[sig(idx)]; w4p[idx] = w4[sig(idx)]; }
}

extern "C" void kernel_launch(void* const* d_in, const int* in_sizes, int n_in,
                              void* d_out, int out_size, void* d_ws, size_t ws_size,
                              hipStream_t stream)
{
  const float* x       = (const float*)d_in[0];
  const int*   src     = (const int*)d_in[1];
  const int*   dst     = (const int*)d_in[2];
  const float* w1      = (const float*)d_in[3];
  const float* b1      = (const float*)d_in[4];
  const float* w2      = (const float*)d_in[5];
  const float* b2      = (const float*)d_in[6];
  const float* w3      = (const float*)d_in[7];
  const float* b3      = (const float*)d_in[8];
  const float* w4      = (const float*)d_in[9];
  const float* b4      = (const float*)d_in[10];
  const float* w_self  = (const float*)d_in[11];
  const float* w_neigh = (const float*)d_in[12];
  const float* bias    = (const float*)d_in[13];

  const int N = in_sizes[0] / 64;
  const int E = in_sizes[1];

  float* A    = (float*)d_out;                    // [N,64]
  float* eout = (float*)d_out + (size_t)N * 64;   // [E]

  char* ws = (char*)d_ws;
  size_t off = 0;
  auto alloc = [&](size_t bytes) {
    void* p = ws + off;
    off = (off + bytes + 255) & ~(size_t)255;
    return p;
  };
  int*    degi   = (int*)alloc((size_t)N * 4);
  int*    rowptr = (int*)alloc((size_t)(N + 1) * 4);
  int*    ord    = (int*)alloc((size_t)E * 4);
  int*    bsum   = (int*)alloc(1024 * 4);
  short8* wcat   = (short8*)alloc((size_t)57344 * 2);
  short8* wfin   = (short8*)alloc((size_t)8192 * 2);
  float*  b1p    = (float*)alloc(256 * 4);
  float*  b2p    = (float*)alloc(128 * 4);
  float*  b3p    = (float*)alloc(64 * 4);
  float*  w4p    = (float*)alloc(64 * 4);
  u16*    msgbuf = (u16*)alloc((size_t)E * 128);

  hipMemsetAsync(degi, 0, (size_t)N * sizeof(int), stream);

  convert_w<<<256, 256, 0, stream>>>(w1, w2, w3, b1, b2, b3, w4, w_self, w_neigh,
                                     (u16*)wcat, (u16*)wfin, b1p, b2p, b3p, w4p);

  deg_hist<<<(E + 255) / 256, 256, 0, stream>>>(dst, degi, ord, E);

  const int nsb = (N + 1023) / 1024;   // <= 256 for N <= 262144
  scan_part<<<nsb, 256, 0, stream>>>(degi, rowptr, bsum, N);
  scan_bsum<<<1, 256, 0, stream>>>(bsum, nsb);
  scan_add<<<nsb, 256, 0, stream>>>(rowptr, bsum, N, E);

  const int nblk = (E + 511) / 512;    // 512 edges per 512-thread block (64/wave)
  edge_mlp<<<nblk, 512, 0, stream>>>(x, src, dst, wcat, b1p, b2p, b3p, w4p, b4,
                                     rowptr, ord, msgbuf, eout, E);

  const int nblk2 = (N + 63) / 64;     // 64 nodes per 256-thread block
  node_agg_mfma<<<nblk2, 256, 0, stream>>>(x, msgbuf, rowptr, wfin, bias, A, N);
}

// Round 17
// 290.587 us; speedup vs baseline: 2.9936x; 1.0505x over previous
//
#include <hip/hip_runtime.h>
#include <hip/hip_bf16.h>

typedef unsigned short u16;
typedef unsigned int   u32;
typedef __attribute__((ext_vector_type(8))) short short8;
typedef __attribute__((ext_vector_type(4))) float f32x4;

__device__ __forceinline__ u16 f2bf(float f) {
  u32 u = __float_as_uint(f);
  u += 0x7FFFu + ((u >> 16) & 1u);   // RNE
  return (u16)(u >> 16);
}
__device__ __forceinline__ float bf2f(u16 h) { return __uint_as_float(((u32)h) << 16); }
// HW packed conversion: v_cvt_pk_bf16_f32 (RNE)
__device__ __forceinline__ u32 pk2(float lo, float hi) {
  union { __hip_bfloat162 h; u32 u; } c;
  c.h = __float22bfloat162_rn(make_float2(lo, hi));
  return c.u;
}
__device__ __forceinline__ float lrelu(float v) { return v > 0.f ? v : 0.01f * v; }

// Channel permutation (verified round 3): physical output position c'=32s+16a+4g+q
// holds logical channel sig(c'). Packed bf16 MFMA outputs fed directly as
// next-layer B-fragments arrive in LOGICAL k-order -> next-layer weights
// permuted only on the output (m) dimension.
__host__ __device__ __forceinline__ int sig(int c) {
  return ((c >> 5) << 5) | ((c & 12) << 1) | (((c >> 4) & 1) << 2) | (c & 3);
}

union U8 { u32 w[4]; short8 v; };

#define MFMA16(A, B, C) __builtin_amdgcn_mfma_f32_16x16x32_bf16(A, B, C, 0, 0, 0)

// wcat chunk bases (short8 units): w1 [0,2048), w2 [2048,6144), w3 [6144,7168).
#define W2_BASE 2048
#define W3_BASE 6144

// msg record layout: position p = 16g + 8h + j holds channel ch = 32h + 8g + j.

// ------------- edge MLP: zero LDS, L2-streamed weights, 256-thr blocks -------
// r15 proved 256-thr blocks co-schedule (42% occ); its failure was (256,4)'s
// 64-VGPR cap. (256,2) caps at 256 -> allocator lands ~120-140 naturally
// (r16: 124), no spill, and 3-4 blocks/CU co-reside by actual usage.
// Weight L2-stream is perf-neutral (r12/r13); shallow prefetch + TLP hides L2.
__global__ __launch_bounds__(256, 2) void edge_mlp(
    const float* __restrict__ x, const int* __restrict__ src, const int* __restrict__ dst,
    const short8* __restrict__ wcat,
    const float* __restrict__ b1p, const float* __restrict__ b2p, const float* __restrict__ b3p,
    const float* __restrict__ w4p, const float* __restrict__ b4,
    const int* __restrict__ rowptr, const int* __restrict__ ord,
    u16* __restrict__ msgbuf, float* __restrict__ eout, int E)
{
  const int tid  = threadIdx.x;
  const int lane = tid & 63;
  const int wv   = tid >> 6;         // 0..3
  const int g    = lane >> 4;        // k-group
  const int r    = lane & 15;        // edge slot / weight row slot
  const int eb   = (blockIdx.x * 4 + wv) * 32;
  const int e0   = eb + r, e1 = eb + 16 + r;
  const int ec0  = e0 < E ? e0 : E - 1;
  const int ec1  = e1 < E ? e1 : E - 1;
  const int sn0 = src[ec0], dn0 = dst[ec0];
  const int sn1 = src[ec1], dn1 = dst[ec1];
  const float b4v = b4[0];

  // ---- issue gather + CSR-slot loads FIRST ----
  const float* xsr0 = x + (size_t)sn0 * 64 + 8 * g;
  const float* xdr0 = x + (size_t)dn0 * 64 + 8 * g;
  const float* xsr1 = x + (size_t)sn1 * 64 + 8 * g;
  const float* xdr1 = x + (size_t)dn1 * 64 + 8 * g;
  const float4 a0s0 = *(const float4*)(xsr0),      a0s1 = *(const float4*)(xsr0 + 4);
  const float4 a0s2 = *(const float4*)(xsr0 + 32), a0s3 = *(const float4*)(xsr0 + 36);
  const float4 a0d0 = *(const float4*)(xdr0),      a0d1 = *(const float4*)(xdr0 + 4);
  const float4 a0d2 = *(const float4*)(xdr0 + 32), a0d3 = *(const float4*)(xdr0 + 36);
  const float4 a1s0 = *(const float4*)(xsr1),      a1s1 = *(const float4*)(xsr1 + 4);
  const float4 a1s2 = *(const float4*)(xsr1 + 32), a1s3 = *(const float4*)(xsr1 + 36);
  const float4 a1d0 = *(const float4*)(xdr1),      a1d1 = *(const float4*)(xdr1 + 4);
  const float4 a1d2 = *(const float4*)(xdr1 + 32), a1d3 = *(const float4*)(xdr1 + 36);
  const int pos0 = rowptr[dn0] + ord[ec0];   // no atomic (r14)
  const int pos1 = rowptr[dn1] + ord[ec1];

  // ---- prefetch w1 tile 0 (L2-resident after first blocks warm it) ----
  short8 w1f0 = wcat[lane];
  short8 w1f1 = wcat[64 + lane];

  // ---- pack B-fragments: d = x[src]-x[dst] (gather regs die here) ----
  U8 bA0, bB0, bA1, bB1;
  bA0.w[0] = pk2(a0s0.x - a0d0.x, a0s0.y - a0d0.y);
  bA0.w[1] = pk2(a0s0.z - a0d0.z, a0s0.w - a0d0.w);
  bA0.w[2] = pk2(a0s1.x - a0d1.x, a0s1.y - a0d1.y);
  bA0.w[3] = pk2(a0s1.z - a0d1.z, a0s1.w - a0d1.w);
  bB0.w[0] = pk2(a0s2.x - a0d2.x, a0s2.y - a0d2.y);
  bB0.w[1] = pk2(a0s2.z - a0d2.z, a0s2.w - a0d2.w);
  bB0.w[2] = pk2(a0s3.x - a0d3.x, a0s3.y - a0d3.y);
  bB0.w[3] = pk2(a0s3.z - a0d3.z, a0s3.w - a0d3.w);
  bA1.w[0] = pk2(a1s0.x - a1d0.x, a1s0.y - a1d0.y);
  bA1.w[1] = pk2(a1s0.z - a1d0.z, a1s0.w - a1d0.w);
  bA1.w[2] = pk2(a1s1.x - a1d1.x, a1s1.y - a1d1.y);
  bA1.w[3] = pk2(a1s1.z - a1d1.z, a1s1.w - a1d1.w);
  bB1.w[0] = pk2(a1s2.x - a1d2.x, a1s2.y - a1d2.y);
  bB1.w[1] = pk2(a1s2.z - a1d2.z, a1s2.w - a1d2.w);
  bB1.w[2] = pk2(a1s3.x - a1d3.x, a1s3.y - a1d3.y);
  bB1.w[3] = pk2(a1s3.z - a1d3.z, a1s3.w - a1d3.w);

  // ---- layer 1: 256 <- 64; w1 streamed, tile-rolling prefetch (r12) ----
  U8 h1A[8], h1B[8];   // quad layout (r14): word w=2t+j -> h1A[w>>2].w[w&3]
  {
    const float* b1l = b1p + 4 * g;
#pragma unroll
    for (int t = 0; t < 16; t++) {
      short8 a0 = w1f0, a1 = w1f1;
      if (t < 15) {
        w1f0 = wcat[(2 * t + 2) * 64 + lane];
        w1f1 = wcat[(2 * t + 3) * 64 + lane];
      }
      f32x4 p = {}, q = {};
      p = MFMA16(a0, bA0.v, p); p = MFMA16(a1, bB0.v, p);
      q = MFMA16(a0, bA1.v, q); q = MFMA16(a1, bB1.v, q);
      float4 bb = *(const float4*)(b1l + 16 * t);
      const int w0 = 2 * t, w1 = 2 * t + 1;
      h1A[w0 >> 2].w[w0 & 3] = pk2(lrelu(p[0] + bb.x), lrelu(p[1] + bb.y));
      h1A[w1 >> 2].w[w1 & 3] = pk2(lrelu(p[2] + bb.z), lrelu(p[3] + bb.w));
      h1B[w0 >> 2].w[w0 & 3] = pk2(lrelu(q[0] + bb.x), lrelu(q[1] + bb.y));
      h1B[w1 >> 2].w[w1 & 3] = pk2(lrelu(q[2] + bb.z), lrelu(q[3] + bb.w));
    }
  }

  // ---- layer 2: 128 <- 256; w2 streamed, depth-2 fragment pipeline ----
  // shallow on purpose (register budget); 3-4 waves/SIMD TLP covers L2 latency.
  U8 h2A[4], h2B[4];
  {
    short8 wf0 = wcat[W2_BASE + lane];
    short8 wf1 = wcat[W2_BASE + 64 + lane];
    const float* b2l = b2p + 4 * g;
#pragma unroll
    for (int t = 0; t < 8; t++) {
      f32x4 p = {}, q = {};
#pragma unroll
      for (int s = 0; s < 8; s += 2) {
        const int f = t * 8 + s;
        short8 a0 = wf0, a1 = wf1;
        if (f + 2 < 64) wf0 = wcat[W2_BASE + (f + 2) * 64 + lane];
        if (f + 3 < 64) wf1 = wcat[W2_BASE + (f + 3) * 64 + lane];
        p = MFMA16(a0, h1A[s].v, p);
        q = MFMA16(a0, h1B[s].v, q);
        p = MFMA16(a1, h1A[s + 1].v, p);
        q = MFMA16(a1, h1B[s + 1].v, q);
      }
      float4 bb = *(const float4*)(b2l + 16 * t);
      const int w0 = 2 * t, w1 = 2 * t + 1;
      h2A[w0 >> 2].w[w0 & 3] = pk2(lrelu(p[0] + bb.x), lrelu(p[1] + bb.y));
      h2A[w1 >> 2].w[w1 & 3] = pk2(lrelu(p[2] + bb.z), lrelu(p[3] + bb.w));
      h2B[w0 >> 2].w[w0 & 3] = pk2(lrelu(q[0] + bb.x), lrelu(q[1] + bb.y));
      h2B[w1 >> 2].w[w1 & 3] = pk2(lrelu(q[2] + bb.z), lrelu(q[3] + bb.w));
    }
  }

  // ---- layer 3 + layer 4 fused; w3 streamed, tile-rolling (r13) ----
  float dot0 = 0.f, dot1 = 0.f;
  {
    short8 w3f = wcat[W3_BASE + lane];
    const float* b3l = b3p + 4 * g;
    const float* w4l = w4p + 4 * g;
#pragma unroll
    for (int t = 0; t < 4; t++) {
      f32x4 p = {}, q = {};
#pragma unroll
      for (int s = 0; s < 4; s++) {
        const int c = t * 4 + s;
        short8 a = w3f;
        if (c < 15) w3f = wcat[W3_BASE + (c + 1) * 64 + lane];
        p = MFMA16(a, h2A[s].v, p);
        q = MFMA16(a, h2B[s].v, q);
      }
      float4 bb = *(const float4*)(b3l + 16 * t);
      float4 ww = *(const float4*)(w4l + 16 * t);
      dot0 += lrelu(p[0] + bb.x) * ww.x + lrelu(p[1] + bb.y) * ww.y
            + lrelu(p[2] + bb.z) * ww.z + lrelu(p[3] + bb.w) * ww.w;
      dot1 += lrelu(q[0] + bb.x) * ww.x + lrelu(q[1] + bb.y) * ww.y
            + lrelu(q[2] + bb.z) * ww.z + lrelu(q[3] + bb.w) * ww.w;
    }
  }
  dot0 += __shfl_xor(dot0, 16); dot0 += __shfl_xor(dot0, 32);
  dot1 += __shfl_xor(dot1, 16); dot1 += __shfl_xor(dot1, 32);
  const float ev0 = 1.f / (1.f + __expf(-(dot0 + b4v)));
  const float ev1 = 1.f / (1.f + __expf(-(dot1 + b4v)));

  // ---- outputs: eout + msg records; x[src] reloaded (L2/L3-hot, r16) ----
  if (g == 0) {
    if (e0 < E) eout[e0] = ev0;
    if (e1 < E) eout[e1] = ev1;
  }
  if (e0 < E) {
    const float4 v0 = *(const float4*)(xsr0);
    const float4 v1 = *(const float4*)(xsr0 + 4);
    const float4 v2 = *(const float4*)(xsr0 + 32);
    const float4 v3 = *(const float4*)(xsr0 + 36);
    u16* mp = msgbuf + (size_t)pos0 * 64 + g * 16;
    U8 m;
    m.w[0] = pk2(ev0 * v0.x, ev0 * v0.y);
    m.w[1] = pk2(ev0 * v0.z, ev0 * v0.w);
    m.w[2] = pk2(ev0 * v1.x, ev0 * v1.y);
    m.w[3] = pk2(ev0 * v1.z, ev0 * v1.w);
    *(short8*)(mp) = m.v;
    m.w[0] = pk2(ev0 * v2.x, ev0 * v2.y);
    m.w[1] = pk2(ev0 * v2.z, ev0 * v2.w);
    m.w[2] = pk2(ev0 * v3.x, ev0 * v3.y);
    m.w[3] = pk2(ev0 * v3.z, ev0 * v3.w);
    *(short8*)(mp + 8) = m.v;
  }
  if (e1 < E) {
    const float4 v0 = *(const float4*)(xsr1);
    const float4 v1 = *(const float4*)(xsr1 + 4);
    const float4 v2 = *(const float4*)(xsr1 + 32);
    const float4 v3 = *(const float4*)(xsr1 + 36);
    u16* mp = msgbuf + (size_t)pos1 * 64 + g * 16;
    U8 m;
    m.w[0] = pk2(ev1 * v0.x, ev1 * v0.y);
    m.w[1] = pk2(ev1 * v0.z, ev1 * v0.w);
    m.w[2] = pk2(ev1 * v1.x, ev1 * v1.y);
    m.w[3] = pk2(ev1 * v1.z, ev1 * v1.w);
    *(short8*)(mp) = m.v;
    m.w[0] = pk2(ev1 * v2.x, ev1 * v2.y);
    m.w[1] = pk2(ev1 * v2.z, ev1 * v2.w);
    m.w[2] = pk2(ev1 * v3.x, ev1 * v3.y);
    m.w[3] = pk2(ev1 * v3.z, ev1 * v3.w);
    *(short8*)(mp + 8) = m.v;
  }
}

// -------- degree histogram + CSR slot assignment (ord = slot within bin) -----
__global__ void deg_hist(const int* __restrict__ dst, int* __restrict__ degi,
                         int* __restrict__ ord, int E)
{
  const int i = blockIdx.x * 256 + threadIdx.x;
  if (i < E) ord[i] = atomicAdd(&degi[dst[i]], 1);
}

// ---------------- CSR build: exclusive scan of degi ----------------
__global__ void scan_part(const int* __restrict__ degi, int* __restrict__ rowptr,
                          int* __restrict__ bsum, int N)
{
  __shared__ int wsum[4];
  const int tid = threadIdx.x, lane = tid & 63, w = tid >> 6;
  const int base = blockIdx.x * 1024 + tid * 4;
  int d0 = 0, d1 = 0, d2 = 0, d3 = 0;
  if (base + 3 < N) {
    int4 v = *(const int4*)(degi + base);
    d0 = v.x; d1 = v.y; d2 = v.z; d3 = v.w;
  } else {
    if (base < N)     d0 = degi[base];
    if (base + 1 < N) d1 = degi[base + 1];
    if (base + 2 < N) d2 = degi[base + 2];
    if (base + 3 < N) d3 = degi[base + 3];
  }
  const int ts = d0 + d1 + d2 + d3;
  int sc = ts;
#pragma unroll
  for (int o = 1; o < 64; o <<= 1) { int v = __shfl_up(sc, o); if (lane >= o) sc += v; }
  if (lane == 63) wsum[w] = sc;
  __syncthreads();
  int woff = 0;
  for (int i = 0; i < w; i++) woff += wsum[i];
  const int ex = woff + sc - ts;
  if (base < N)     rowptr[base]     = ex;
  if (base + 1 < N) rowptr[base + 1] = ex + d0;
  if (base + 2 < N) rowptr[base + 2] = ex + d0 + d1;
  if (base + 3 < N) rowptr[base + 3] = ex + d0 + d1 + d2;
  if (tid == 255) bsum[blockIdx.x] = woff + sc;
}

__global__ void scan_bsum(int* __restrict__ bsum, int nb)  // nb <= 256
{
  __shared__ int wsum[4];
  const int tid = threadIdx.x, lane = tid & 63, w = tid >> 6;
  const int v = tid < nb ? bsum[tid] : 0;
  int sc = v;
#pragma unroll
  for (int o = 1; o < 64; o <<= 1) { int t = __shfl_up(sc, o); if (lane >= o) sc += t; }
  if (lane == 63) wsum[w] = sc;
  __syncthreads();
  int woff = 0;
  for (int i = 0; i < w; i++) woff += wsum[i];
  if (tid < nb) bsum[tid] = woff + sc - v;
}

__global__ void scan_add(int* __restrict__ rowptr, const int* __restrict__ bsum,
                         int N, int E)
{
  const int base = blockIdx.x * 1024 + threadIdx.x * 4;
  const int off = bsum[blockIdx.x];
#pragma unroll
  for (int i = 0; i < 4; i++)
    if (base + i < N) rowptr[base + i] += off;
  if (blockIdx.x == 0 && threadIdx.x == 0) rowptr[N] = E;
}

// -------- aggregate + finalize on MFMA: 16 nodes/wave, 4 waves/block --------
__global__ __launch_bounds__(256, 4) void node_agg_mfma(
    const float* __restrict__ x, const u16* __restrict__ msgbuf,
    const int* __restrict__ rowptr, const short8* __restrict__ wfin,
    const float* __restrict__ bias, float* __restrict__ A, int N)
{
  __shared__ short8 ldsW[1024];        // 16 KiB: [w_self|w_neigh] fragment-linear
  __shared__ float  nbuf[4][16][68];   // 17.4 KiB: per-wave node means (padded)
  const int tid = threadIdx.x, wv = tid >> 6, lane = tid & 63;
  const int g = lane >> 4, r = lane & 15;
  for (int i = tid; i < 1024; i += 256) ldsW[i] = wfin[i];

  const int n0 = (blockIdx.x * 4 + wv) * 16;
  const int nr = (n0 + r) < N ? (n0 + r) : N - 1;
  const float* xp = x + (size_t)nr * 64 + 8 * g;
  const float4 xf0 = *(const float4*)(xp);
  const float4 xf1 = *(const float4*)(xp + 4);
  const float4 xf2 = *(const float4*)(xp + 32);
  const float4 xf3 = *(const float4*)(xp + 36);
  int rp = 0;
  if (lane < 17) rp = rowptr[min(n0 + lane, N)];
  const int cch = (((lane >> 3) & 1) << 5) | ((lane >> 4) << 3) | (lane & 7);
  for (int rr = 0; rr < 16; rr++) {
    const int s = __shfl(rp, rr);
    const int t = __shfl(rp, rr + 1);
    float acc = 0.f;
    for (int j = s; j < t; j += 4) {
      const int j1 = (j + 1 < t) ? j + 1 : j;
      const int j2 = (j + 2 < t) ? j + 2 : j;
      const int j3 = (j + 3 < t) ? j + 3 : j;
      const float v0 = bf2f(msgbuf[(size_t)j  * 64 + lane]);
      const float v1 = bf2f(msgbuf[(size_t)j1 * 64 + lane]);
      const float v2 = bf2f(msgbuf[(size_t)j2 * 64 + lane]);
      const float v3 = bf2f(msgbuf[(size_t)j3 * 64 + lane]);
      const float m1 = (j + 1 < t) ? 1.f : 0.f;
      const float m2 = (j + 2 < t) ? 1.f : 0.f;
      const float m3 = (j + 3 < t) ? 1.f : 0.f;
      acc += v0 + m1 * v1 + m2 * v2 + m3 * v3;
    }
    const float inv = 1.f / fmaxf((float)(t - s), 1.f);
    nbuf[wv][rr][cch] = acc * inv;   // logical channel order
  }
  __syncthreads();   // covers ldsW staging (nbuf is per-wave)

  U8 bf0, bf1, bf2q, bf3q;
  bf0.w[0] = pk2(xf0.x, xf0.y); bf0.w[1] = pk2(xf0.z, xf0.w);
  bf0.w[2] = pk2(xf1.x, xf1.y); bf0.w[3] = pk2(xf1.z, xf1.w);
  bf1.w[0] = pk2(xf2.x, xf2.y); bf1.w[1] = pk2(xf2.z, xf2.w);
  bf1.w[2] = pk2(xf3.x, xf3.y); bf1.w[3] = pk2(xf3.z, xf3.w);
  {
    const float* nb = nbuf[wv][r];
    const float4 n0v = *(const float4*)(nb + 8 * g);
    const float4 n1v = *(const float4*)(nb + 8 * g + 4);
    const float4 n2v = *(const float4*)(nb + 32 + 8 * g);
    const float4 n3v = *(const float4*)(nb + 32 + 8 * g + 4);
    bf2q.w[0] = pk2(n0v.x, n0v.y); bf2q.w[1] = pk2(n0v.z, n0v.w);
    bf2q.w[2] = pk2(n1v.x, n1v.y); bf2q.w[3] = pk2(n1v.z, n1v.w);
    bf3q.w[0] = pk2(n2v.x, n2v.y); bf3q.w[1] = pk2(n2v.z, n2v.w);
    bf3q.w[2] = pk2(n3v.x, n3v.y); bf3q.w[3] = pk2(n3v.z, n3v.w);
  }

  f32x4 acct[4] = {};
#pragma unroll
  for (int t = 0; t < 4; t++) {
    acct[t] = MFMA16(ldsW[(t * 4 + 0) * 64 + lane], bf0.v,  acct[t]);
    acct[t] = MFMA16(ldsW[(t * 4 + 1) * 64 + lane], bf1.v,  acct[t]);
    acct[t] = MFMA16(ldsW[(t * 4 + 2) * 64 + lane], bf2q.v, acct[t]);
    acct[t] = MFMA16(ldsW[(t * 4 + 3) * 64 + lane], bf3q.v, acct[t]);
  }

  f32x4 av[4];
  float ss = 0.f;
#pragma unroll
  for (int t = 0; t < 4; t++) {
    const float4 bb = *(const float4*)(bias + 16 * t + 4 * g);
    av[t][0] = lrelu(acct[t][0] + bb.x);
    av[t][1] = lrelu(acct[t][1] + bb.y);
    av[t][2] = lrelu(acct[t][2] + bb.z);
    av[t][3] = lrelu(acct[t][3] + bb.w);
    ss += av[t][0] * av[t][0] + av[t][1] * av[t][1]
        + av[t][2] * av[t][2] + av[t][3] * av[t][3];
  }
  ss += __shfl_xor(ss, 16); ss += __shfl_xor(ss, 32);
  const float rn = 1.f / fmaxf(sqrtf(ss), 1e-12f);
  if (n0 + r < N) {
    float* ap = A + (size_t)(n0 + r) * 64 + 4 * g;
#pragma unroll
    for (int t = 0; t < 4; t++) {
      float4 o;
      o.x = av[t][0] * rn; o.y = av[t][1] * rn;
      o.z = av[t][2] * rn; o.w = av[t][3] * rn;
      *(float4*)(ap + 16 * t) = o;
    }
  }
}

// --------- weight conversion: fragment-linear chunk layouts ----
__global__ void convert_w(const float* __restrict__ w1, const float* __restrict__ w2,
                          const float* __restrict__ w3,
                          const float* __restrict__ b1, const float* __restrict__ b2,
                          const float* __restrict__ b3, const float* __restrict__ w4,
                          const float* __restrict__ w_self, const float* __restrict__ w_neigh,
                          u16* __restrict__ wcat, u16* __restrict__ wfin,
                          float* __restrict__ b1p, float* __restrict__ b2p,
                          float* __restrict__ b3p, float* __restrict__ w4p)
{
  const int idx = blockIdx.x * 256 + threadIdx.x;
  if (idx < 57344) {
    const float* w; int K, nsteps, loc;
    if (idx < 16384)      { loc = idx;         w = w1; K = 64;  nsteps = 2; }
    else if (idx < 49152) { loc = idx - 16384; w = w2; K = 256; nsteps = 8; }
    else                  { loc = idx - 49152; w = w3; K = 128; nsteps = 4; }
    const int chunk = loc >> 9;
    const int lane  = (loc >> 3) & 63;
    const int j     = loc & 7;
    const int t = chunk / nsteps, s = chunk % nsteps;
    const int m = sig(t * 16 + (lane & 15));
    const int k = s * 32 + (lane >> 4) * 8 + j;
    wcat[idx] = f2bf(w[m * K + k]);
  } else if (idx < 65536) {
    // wfin: [w_self | w_neigh] as 64x128, chunk c = t*4+s, NO permutation
    const int o = idx - 57344;
    const int c = o >> 9, lane = (o >> 3) & 63, j = o & 7;
    const int t = c >> 2, s = c & 3;
    const int m = 16 * t + (lane & 15);
    const int k = 32 * s + ((lane >> 4) << 3) + j;
    wfin[o] = f2bf(k < 64 ? w_self[m * 64 + k] : w_neigh[m * 64 + (k - 64)]);
  }
  if (idx < 256) b1p[idx] = b1[sig(idx)];
  if (idx < 128) b2p[idx] = b2[sig(idx)];
  if (idx < 64)  { b3p[idx] = b3[sig(idx)]; w4p[idx] = w4[sig(idx)]; }
}

extern "C" void kernel_launch(void* const* d_in, const int* in_sizes, int n_in,
                              void* d_out, int out_size, void* d_ws, size_t ws_size,
                              hipStream_t stream)
{
  const float* x       = (const float*)d_in[0];
  const int*   src     = (const int*)d_in[1];
  const int*   dst     = (const int*)d_in[2];
  const float* w1      = (const float*)d_in[3];
  const float* b1      = (const float*)d_in[4];
  const float* w2      = (const float*)d_in[5];
  const float* b2      = (const float*)d_in[6];
  const float* w3      = (const float*)d_in[7];
  const float* b3      = (const float*)d_in[8];
  const float* w4      = (const float*)d_in[9];
  const float* b4      = (const float*)d_in[10];
  const float* w_self  = (const float*)d_in[11];
  const float* w_neigh = (const float*)d_in[12];
  const float* bias    = (const float*)d_in[13];

  const int N = in_sizes[0] / 64;
  const int E = in_sizes[1];

  float* A    = (float*)d_out;                    // [N,64]
  float* eout = (float*)d_out + (size_t)N * 64;   // [E]

  char* ws = (char*)d_ws;
  size_t off = 0;
  auto alloc = [&](size_t bytes) {
    void* p = ws + off;
    off = (off + bytes + 255) & ~(size_t)255;
    return p;
  };
  int*    degi   = (int*)alloc((size_t)N * 4);
  int*    rowptr = (int*)alloc((size_t)(N + 1) * 4);
  int*    ord    = (int*)alloc((size_t)E * 4);
  int*    bsum   = (int*)alloc(1024 * 4);
  short8* wcat   = (short8*)alloc((size_t)57344 * 2);
  short8* wfin   = (short8*)alloc((size_t)8192 * 2);
  float*  b1p    = (float*)alloc(256 * 4);
  float*  b2p    = (float*)alloc(128 * 4);
  float*  b3p    = (float*)alloc(64 * 4);
  float*  w4p    = (float*)alloc(64 * 4);
  u16*    msgbuf = (u16*)alloc((size_t)E * 128);

  hipMemsetAsync(degi, 0, (size_t)N * sizeof(int), stream);

  convert_w<<<256, 256, 0, stream>>>(w1, w2, w3, b1, b2, b3, w4, w_self, w_neigh,
                                     (u16*)wcat, (u16*)wfin, b1p, b2p, b3p, w4p);

  deg_hist<<<(E + 255) / 256, 256, 0, stream>>>(dst, degi, ord, E);

  const int nsb = (N + 1023) / 1024;   // <= 256 for N <= 262144
  scan_part<<<nsb, 256, 0, stream>>>(degi, rowptr, bsum, N);
  scan_bsum<<<1, 256, 0, stream>>>(bsum, nsb);
  scan_add<<<nsb, 256, 0, stream>>>(rowptr, bsum, N, E);

  const int nblk = (E + 127) / 128;    // 128 edges per 256-thread block
  edge_mlp<<<nblk, 256, 0, stream>>>(x, src, dst, wcat, b1p, b2p, b3p, w4p, b4,
                                     rowptr, ord, msgbuf, eout, E);

  const int nblk2 = (N + 63) / 64;     // 64 nodes per 256-thread block
  node_agg_mfma<<<nblk2, 256, 0, stream>>>(x, msgbuf, rowptr, wfin, bias, A, N);
}

// Round 18
// 287.099 us; speedup vs baseline: 3.0300x; 1.0121x over previous
//
#include <hip/hip_runtime.h>
#include <hip/hip_bf16.h>

typedef unsigned short u16;
typedef unsigned int   u32;
typedef __attribute__((ext_vector_type(8))) short short8;
typedef __attribute__((ext_vector_type(4))) float f32x4;

__device__ __forceinline__ u16 f2bf(float f) {
  u32 u = __float_as_uint(f);
  u += 0x7FFFu + ((u >> 16) & 1u);   // RNE
  return (u16)(u >> 16);
}
__device__ __forceinline__ float bf2f(u16 h) { return __uint_as_float(((u32)h) << 16); }
// HW packed conversion: v_cvt_pk_bf16_f32 (RNE)
__device__ __forceinline__ u32 pk2(float lo, float hi) {
  union { __hip_bfloat162 h; u32 u; } c;
  c.h = __float22bfloat162_rn(make_float2(lo, hi));
  return c.u;
}
// lrelu as 2 guaranteed VALU ops (mul + max); correct for both signs.
__device__ __forceinline__ float lrelu(float v) { return fmaxf(v, 0.01f * v); }

// Channel permutation (verified round 3): physical output position c'=32s+16a+4g+q
// holds logical channel sig(c'). Packed bf16 MFMA outputs fed directly as
// next-layer B-fragments arrive in LOGICAL k-order -> next-layer weights
// permuted only on the output (m) dimension.
__host__ __device__ __forceinline__ int sig(int c) {
  return ((c >> 5) << 5) | ((c & 12) << 1) | (((c >> 4) & 1) << 2) | (c & 3);
}

union U8 { u32 w[4]; short8 v; };

#define MFMA16(A, B, C) __builtin_amdgcn_mfma_f32_16x16x32_bf16(A, B, C, 0, 0, 0)

// wcat chunk bases (short8 units): w1 [0,2048), w2 [2048,6144), w3 [6144,7168).
#define W2_BASE 2048
#define W3_BASE 6144

// msg record layout: position p = 16g + 8h + j holds channel ch = 32h + 8g + j.

// ------------- edge MLP: zero LDS, L2-streamed weights, 256-thr blocks -------
// r17: (256,2) -> 80 VGPR, no spill, 33% occ, 227us. (256,3) requests one more
// resident block (cap ~170 >> 80 in use -> no spill risk). Bias moved into the
// MFMA accumulator init (C-in = per-row bias) kills ~220 VALU adds/wave.
__global__ __launch_bounds__(256, 3) void edge_mlp(
    const float* __restrict__ x, const int* __restrict__ src, const int* __restrict__ dst,
    const short8* __restrict__ wcat,
    const float* __restrict__ b1p, const float* __restrict__ b2p, const float* __restrict__ b3p,
    const float* __restrict__ w4p, const float* __restrict__ b4,
    const int* __restrict__ rowptr, const int* __restrict__ ord,
    u16* __restrict__ msgbuf, float* __restrict__ eout, int E)
{
  const int tid  = threadIdx.x;
  const int lane = tid & 63;
  const int wv   = tid >> 6;         // 0..3
  const int g    = lane >> 4;        // k-group
  const int r    = lane & 15;        // edge slot / weight row slot
  const int eb   = (blockIdx.x * 4 + wv) * 32;
  const int e0   = eb + r, e1 = eb + 16 + r;
  const int ec0  = e0 < E ? e0 : E - 1;
  const int ec1  = e1 < E ? e1 : E - 1;
  const int sn0 = src[ec0], dn0 = dst[ec0];
  const int sn1 = src[ec1], dn1 = dst[ec1];
  const float b4v = b4[0];

  // ---- issue gather + CSR-slot loads FIRST ----
  const float* xsr0 = x + (size_t)sn0 * 64 + 8 * g;
  const float* xdr0 = x + (size_t)dn0 * 64 + 8 * g;
  const float* xsr1 = x + (size_t)sn1 * 64 + 8 * g;
  const float* xdr1 = x + (size_t)dn1 * 64 + 8 * g;
  const float4 a0s0 = *(const float4*)(xsr0),      a0s1 = *(const float4*)(xsr0 + 4);
  const float4 a0s2 = *(const float4*)(xsr0 + 32), a0s3 = *(const float4*)(xsr0 + 36);
  const float4 a0d0 = *(const float4*)(xdr0),      a0d1 = *(const float4*)(xdr0 + 4);
  const float4 a0d2 = *(const float4*)(xdr0 + 32), a0d3 = *(const float4*)(xdr0 + 36);
  const float4 a1s0 = *(const float4*)(xsr1),      a1s1 = *(const float4*)(xsr1 + 4);
  const float4 a1s2 = *(const float4*)(xsr1 + 32), a1s3 = *(const float4*)(xsr1 + 36);
  const float4 a1d0 = *(const float4*)(xdr1),      a1d1 = *(const float4*)(xdr1 + 4);
  const float4 a1d2 = *(const float4*)(xdr1 + 32), a1d3 = *(const float4*)(xdr1 + 36);
  const int pos0 = rowptr[dn0] + ord[ec0];   // no atomic (r14)
  const int pos1 = rowptr[dn1] + ord[ec1];

  // ---- prefetch w1 tile 0 (L2-resident) ----
  short8 w1f0 = wcat[lane];
  short8 w1f1 = wcat[64 + lane];

  // ---- pack B-fragments: d = x[src]-x[dst] (gather regs die here) ----
  U8 bA0, bB0, bA1, bB1;
  bA0.w[0] = pk2(a0s0.x - a0d0.x, a0s0.y - a0d0.y);
  bA0.w[1] = pk2(a0s0.z - a0d0.z, a0s0.w - a0d0.w);
  bA0.w[2] = pk2(a0s1.x - a0d1.x, a0s1.y - a0d1.y);
  bA0.w[3] = pk2(a0s1.z - a0d1.z, a0s1.w - a0d1.w);
  bB0.w[0] = pk2(a0s2.x - a0d2.x, a0s2.y - a0d2.y);
  bB0.w[1] = pk2(a0s2.z - a0d2.z, a0s2.w - a0d2.w);
  bB0.w[2] = pk2(a0s3.x - a0d3.x, a0s3.y - a0d3.y);
  bB0.w[3] = pk2(a0s3.z - a0d3.z, a0s3.w - a0d3.w);
  bA1.w[0] = pk2(a1s0.x - a1d0.x, a1s0.y - a1d0.y);
  bA1.w[1] = pk2(a1s0.z - a1d0.z, a1s0.w - a1d0.w);
  bA1.w[2] = pk2(a1s1.x - a1d1.x, a1s1.y - a1d1.y);
  bA1.w[3] = pk2(a1s1.z - a1d1.z, a1s1.w - a1d1.w);
  bB1.w[0] = pk2(a1s2.x - a1d2.x, a1s2.y - a1d2.y);
  bB1.w[1] = pk2(a1s2.z - a1d2.z, a1s2.w - a1d2.w);
  bB1.w[2] = pk2(a1s3.x - a1d3.x, a1s3.y - a1d3.y);
  bB1.w[3] = pk2(a1s3.z - a1d3.z, a1s3.w - a1d3.w);

  // ---- layer 1: 256 <- 64; w1 streamed; bias preloaded into C-in ----
  U8 h1A[8], h1B[8];   // quad layout (r14): word w=2t+j -> h1A[w>>2].w[w&3]
  {
    const float* b1l = b1p + 4 * g;
#pragma unroll
    for (int t = 0; t < 16; t++) {
      short8 a0 = w1f0, a1 = w1f1;
      if (t < 15) {
        w1f0 = wcat[(2 * t + 2) * 64 + lane];
        w1f1 = wcat[(2 * t + 3) * 64 + lane];
      }
      float4 bb = *(const float4*)(b1l + 16 * t);
      f32x4 p = {bb.x, bb.y, bb.z, bb.w};
      f32x4 q = p;
      p = MFMA16(a0, bA0.v, p); p = MFMA16(a1, bB0.v, p);
      q = MFMA16(a0, bA1.v, q); q = MFMA16(a1, bB1.v, q);
      const int w0 = 2 * t, w1 = 2 * t + 1;
      h1A[w0 >> 2].w[w0 & 3] = pk2(lrelu(p[0]), lrelu(p[1]));
      h1A[w1 >> 2].w[w1 & 3] = pk2(lrelu(p[2]), lrelu(p[3]));
      h1B[w0 >> 2].w[w0 & 3] = pk2(lrelu(q[0]), lrelu(q[1]));
      h1B[w1 >> 2].w[w1 & 3] = pk2(lrelu(q[2]), lrelu(q[3]));
    }
  }

  // ---- layer 2: 128 <- 256; w2 streamed depth-2; bias in C-in ----
  U8 h2A[4], h2B[4];
  {
    short8 wf0 = wcat[W2_BASE + lane];
    short8 wf1 = wcat[W2_BASE + 64 + lane];
    const float* b2l = b2p + 4 * g;
#pragma unroll
    for (int t = 0; t < 8; t++) {
      float4 bb = *(const float4*)(b2l + 16 * t);
      f32x4 p = {bb.x, bb.y, bb.z, bb.w};
      f32x4 q = p;
#pragma unroll
      for (int s = 0; s < 8; s += 2) {
        const int f = t * 8 + s;
        short8 a0 = wf0, a1 = wf1;
        if (f + 2 < 64) wf0 = wcat[W2_BASE + (f + 2) * 64 + lane];
        if (f + 3 < 64) wf1 = wcat[W2_BASE + (f + 3) * 64 + lane];
        p = MFMA16(a0, h1A[s].v, p);
        q = MFMA16(a0, h1B[s].v, q);
        p = MFMA16(a1, h1A[s + 1].v, p);
        q = MFMA16(a1, h1B[s + 1].v, q);
      }
      const int w0 = 2 * t, w1 = 2 * t + 1;
      h2A[w0 >> 2].w[w0 & 3] = pk2(lrelu(p[0]), lrelu(p[1]));
      h2A[w1 >> 2].w[w1 & 3] = pk2(lrelu(p[2]), lrelu(p[3]));
      h2B[w0 >> 2].w[w0 & 3] = pk2(lrelu(q[0]), lrelu(q[1]));
      h2B[w1 >> 2].w[w1 & 3] = pk2(lrelu(q[2]), lrelu(q[3]));
    }
  }

  // ---- layer 3 + layer 4 fused; w3 streamed; bias in C-in ----
  float dot0 = 0.f, dot1 = 0.f;
  {
    short8 w3f = wcat[W3_BASE + lane];
    const float* b3l = b3p + 4 * g;
    const float* w4l = w4p + 4 * g;
#pragma unroll
    for (int t = 0; t < 4; t++) {
      float4 bb = *(const float4*)(b3l + 16 * t);
      f32x4 p = {bb.x, bb.y, bb.z, bb.w};
      f32x4 q = p;
#pragma unroll
      for (int s = 0; s < 4; s++) {
        const int c = t * 4 + s;
        short8 a = w3f;
        if (c < 15) w3f = wcat[W3_BASE + (c + 1) * 64 + lane];
        p = MFMA16(a, h2A[s].v, p);
        q = MFMA16(a, h2B[s].v, q);
      }
      float4 ww = *(const float4*)(w4l + 16 * t);
      dot0 += lrelu(p[0]) * ww.x + lrelu(p[1]) * ww.y
            + lrelu(p[2]) * ww.z + lrelu(p[3]) * ww.w;
      dot1 += lrelu(q[0]) * ww.x + lrelu(q[1]) * ww.y
            + lrelu(q[2]) * ww.z + lrelu(q[3]) * ww.w;
    }
  }
  dot0 += __shfl_xor(dot0, 16); dot0 += __shfl_xor(dot0, 32);
  dot1 += __shfl_xor(dot1, 16); dot1 += __shfl_xor(dot1, 32);
  const float ev0 = 1.f / (1.f + __expf(-(dot0 + b4v)));
  const float ev1 = 1.f / (1.f + __expf(-(dot1 + b4v)));

  // ---- outputs: eout + msg records; x[src] reloaded (L2/L3-hot, r16) ----
  if (g == 0) {
    if (e0 < E) eout[e0] = ev0;
    if (e1 < E) eout[e1] = ev1;
  }
  if (e0 < E) {
    const float4 v0 = *(const float4*)(xsr0);
    const float4 v1 = *(const float4*)(xsr0 + 4);
    const float4 v2 = *(const float4*)(xsr0 + 32);
    const float4 v3 = *(const float4*)(xsr0 + 36);
    u16* mp = msgbuf + (size_t)pos0 * 64 + g * 16;
    U8 m;
    m.w[0] = pk2(ev0 * v0.x, ev0 * v0.y);
    m.w[1] = pk2(ev0 * v0.z, ev0 * v0.w);
    m.w[2] = pk2(ev0 * v1.x, ev0 * v1.y);
    m.w[3] = pk2(ev0 * v1.z, ev0 * v1.w);
    *(short8*)(mp) = m.v;
    m.w[0] = pk2(ev0 * v2.x, ev0 * v2.y);
    m.w[1] = pk2(ev0 * v2.z, ev0 * v2.w);
    m.w[2] = pk2(ev0 * v3.x, ev0 * v3.y);
    m.w[3] = pk2(ev0 * v3.z, ev0 * v3.w);
    *(short8*)(mp + 8) = m.v;
  }
  if (e1 < E) {
    const float4 v0 = *(const float4*)(xsr1);
    const float4 v1 = *(const float4*)(xsr1 + 4);
    const float4 v2 = *(const float4*)(xsr1 + 32);
    const float4 v3 = *(const float4*)(xsr1 + 36);
    u16* mp = msgbuf + (size_t)pos1 * 64 + g * 16;
    U8 m;
    m.w[0] = pk2(ev1 * v0.x, ev1 * v0.y);
    m.w[1] = pk2(ev1 * v0.z, ev1 * v0.w);
    m.w[2] = pk2(ev1 * v1.x, ev1 * v1.y);
    m.w[3] = pk2(ev1 * v1.z, ev1 * v1.w);
    *(short8*)(mp) = m.v;
    m.w[0] = pk2(ev1 * v2.x, ev1 * v2.y);
    m.w[1] = pk2(ev1 * v2.z, ev1 * v2.w);
    m.w[2] = pk2(ev1 * v3.x, ev1 * v3.y);
    m.w[3] = pk2(ev1 * v3.z, ev1 * v3.w);
    *(short8*)(mp + 8) = m.v;
  }
}

// -------- degree histogram + CSR slot assignment (ord = slot within bin) -----
__global__ void deg_hist(const int* __restrict__ dst, int* __restrict__ degi,
                         int* __restrict__ ord, int E)
{
  const int i = blockIdx.x * 256 + threadIdx.x;
  if (i < E) ord[i] = atomicAdd(&degi[dst[i]], 1);
}

// ---------------- CSR build: exclusive scan of degi ----------------
__global__ void scan_part(const int* __restrict__ degi, int* __restrict__ rowptr,
                          int* __restrict__ bsum, int N)
{
  __shared__ int wsum[4];
  const int tid = threadIdx.x, lane = tid & 63, w = tid >> 6;
  const int base = blockIdx.x * 1024 + tid * 4;
  int d0 = 0, d1 = 0, d2 = 0, d3 = 0;
  if (base + 3 < N) {
    int4 v = *(const int4*)(degi + base);
    d0 = v.x; d1 = v.y; d2 = v.z; d3 = v.w;
  } else {
    if (base < N)     d0 = degi[base];
    if (base + 1 < N) d1 = degi[base + 1];
    if (base + 2 < N) d2 = degi[base + 2];
    if (base + 3 < N) d3 = degi[base + 3];
  }
  const int ts = d0 + d1 + d2 + d3;
  int sc = ts;
#pragma unroll
  for (int o = 1; o < 64; o <<= 1) { int v = __shfl_up(sc, o); if (lane >= o) sc += v; }
  if (lane == 63) wsum[w] = sc;
  __syncthreads();
  int woff = 0;
  for (int i = 0; i < w; i++) woff += wsum[i];
  const int ex = woff + sc - ts;
  if (base < N)     rowptr[base]     = ex;
  if (base + 1 < N) rowptr[base + 1] = ex + d0;
  if (base + 2 < N) rowptr[base + 2] = ex + d0 + d1;
  if (base + 3 < N) rowptr[base + 3] = ex + d0 + d1 + d2;
  if (tid == 255) bsum[blockIdx.x] = woff + sc;
}

__global__ void scan_bsum(int* __restrict__ bsum, int nb)  // nb <= 256
{
  __shared__ int wsum[4];
  const int tid = threadIdx.x, lane = tid & 63, w = tid >> 6;
  const int v = tid < nb ? bsum[tid] : 0;
  int sc = v;
#pragma unroll
  for (int o = 1; o < 64; o <<= 1) { int t = __shfl_up(sc, o); if (lane >= o) sc += t; }
  if (lane == 63) wsum[w] = sc;
  __syncthreads();
  int woff = 0;
  for (int i = 0; i < w; i++) woff += wsum[i];
  if (tid < nb) bsum[tid] = woff + sc - v;
}

__global__ void scan_add(int* __restrict__ rowptr, const int* __restrict__ bsum,
                         int N, int E)
{
  const int base = blockIdx.x * 1024 + threadIdx.x * 4;
  const int off = bsum[blockIdx.x];
#pragma unroll
  for (int i = 0; i < 4; i++)
    if (base + i < N) rowptr[base + i] += off;
  if (blockIdx.x == 0 && threadIdx.x == 0) rowptr[N] = E;
}

// -------- aggregate + finalize on MFMA: 16 nodes/wave, 4 waves/block --------
__global__ __launch_bounds__(256, 4) void node_agg_mfma(
    const float* __restrict__ x, const u16* __restrict__ msgbuf,
    const int* __restrict__ rowptr, const short8* __restrict__ wfin,
    const float* __restrict__ bias, float* __restrict__ A, int N)
{
  __shared__ short8 ldsW[1024];        // 16 KiB: [w_self|w_neigh] fragment-linear
  __shared__ float  nbuf[4][16][68];   // 17.4 KiB: per-wave node means (padded)
  const int tid = threadIdx.x, wv = tid >> 6, lane = tid & 63;
  const int g = lane >> 4, r = lane & 15;
  for (int i = tid; i < 1024; i += 256) ldsW[i] = wfin[i];

  const int n0 = (blockIdx.x * 4 + wv) * 16;
  const int nr = (n0 + r) < N ? (n0 + r) : N - 1;
  const float* xp = x + (size_t)nr * 64 + 8 * g;
  const float4 xf0 = *(const float4*)(xp);
  const float4 xf1 = *(const float4*)(xp + 4);
  const float4 xf2 = *(const float4*)(xp + 32);
  const float4 xf3 = *(const float4*)(xp + 36);
  int rp = 0;
  if (lane < 17) rp = rowptr[min(n0 + lane, N)];
  const int cch = (((lane >> 3) & 1) << 5) | ((lane >> 4) << 3) | (lane & 7);
  for (int rr = 0; rr < 16; rr++) {
    const int s = __shfl(rp, rr);
    const int t = __shfl(rp, rr + 1);
    float acc = 0.f;
    for (int j = s; j < t; j += 4) {
      const int j1 = (j + 1 < t) ? j + 1 : j;
      const int j2 = (j + 2 < t) ? j + 2 : j;
      const int j3 = (j + 3 < t) ? j + 3 : j;
      const float v0 = bf2f(msgbuf[(size_t)j  * 64 + lane]);
      const float v1 = bf2f(msgbuf[(size_t)j1 * 64 + lane]);
      const float v2 = bf2f(msgbuf[(size_t)j2 * 64 + lane]);
      const float v3 = bf2f(msgbuf[(size_t)j3 * 64 + lane]);
      const float m1 = (j + 1 < t) ? 1.f : 0.f;
      const float m2 = (j + 2 < t) ? 1.f : 0.f;
      const float m3 = (j + 3 < t) ? 1.f : 0.f;
      acc += v0 + m1 * v1 + m2 * v2 + m3 * v3;
    }
    const float inv = 1.f / fmaxf((float)(t - s), 1.f);
    nbuf[wv][rr][cch] = acc * inv;   // logical channel order
  }
  __syncthreads();   // covers ldsW staging (nbuf is per-wave)

  U8 bf0, bf1, bf2q, bf3q;
  bf0.w[0] = pk2(xf0.x, xf0.y); bf0.w[1] = pk2(xf0.z, xf0.w);
  bf0.w[2] = pk2(xf1.x, xf1.y); bf0.w[3] = pk2(xf1.z, xf1.w);
  bf1.w[0] = pk2(xf2.x, xf2.y); bf1.w[1] = pk2(xf2.z, xf2.w);
  bf1.w[2] = pk2(xf3.x, xf3.y); bf1.w[3] = pk2(xf3.z, xf3.w);
  {
    const float* nb = nbuf[wv][r];
    const float4 n0v = *(const float4*)(nb + 8 * g);
    const float4 n1v = *(const float4*)(nb + 8 * g + 4);
    const float4 n2v = *(const float4*)(nb + 32 + 8 * g);
    const float4 n3v = *(const float4*)(nb + 32 + 8 * g + 4);
    bf2q.w[0] = pk2(n0v.x, n0v.y); bf2q.w[1] = pk2(n0v.z, n0v.w);
    bf2q.w[2] = pk2(n1v.x, n1v.y); bf2q.w[3] = pk2(n1v.z, n1v.w);
    bf3q.w[0] = pk2(n2v.x, n2v.y); bf3q.w[1] = pk2(n2v.z, n2v.w);
    bf3q.w[2] = pk2(n3v.x, n3v.y); bf3q.w[3] = pk2(n3v.z, n3v.w);
  }

  f32x4 acct[4] = {};
#pragma unroll
  for (int t = 0; t < 4; t++) {
    acct[t] = MFMA16(ldsW[(t * 4 + 0) * 64 + lane], bf0.v,  acct[t]);
    acct[t] = MFMA16(ldsW[(t * 4 + 1) * 64 + lane], bf1.v,  acct[t]);
    acct[t] = MFMA16(ldsW[(t * 4 + 2) * 64 + lane], bf2q.v, acct[t]);
    acct[t] = MFMA16(ldsW[(t * 4 + 3) * 64 + lane], bf3q.v, acct[t]);
  }

  f32x4 av[4];
  float ss = 0.f;
#pragma unroll
  for (int t = 0; t < 4; t++) {
    const float4 bb = *(const float4*)(bias + 16 * t + 4 * g);
    av[t][0] = lrelu(acct[t][0] + bb.x);
    av[t][1] = lrelu(acct[t][1] + bb.y);
    av[t][2] = lrelu(acct[t][2] + bb.z);
    av[t][3] = lrelu(acct[t][3] + bb.w);
    ss += av[t][0] * av[t][0] + av[t][1] * av[t][1]
        + av[t][2] * av[t][2] + av[t][3] * av[t][3];
  }
  ss += __shfl_xor(ss, 16); ss += __shfl_xor(ss, 32);
  const float rn = 1.f / fmaxf(sqrtf(ss), 1e-12f);
  if (n0 + r < N) {
    float* ap = A + (size_t)(n0 + r) * 64 + 4 * g;
#pragma unroll
    for (int t = 0; t < 4; t++) {
      float4 o;
      o.x = av[t][0] * rn; o.y = av[t][1] * rn;
      o.z = av[t][2] * rn; o.w = av[t][3] * rn;
      *(float4*)(ap + 16 * t) = o;
    }
  }
}

// --------- weight conversion: fragment-linear chunk layouts ----
__global__ void convert_w(const float* __restrict__ w1, const float* __restrict__ w2,
                          const float* __restrict__ w3,
                          const float* __restrict__ b1, const float* __restrict__ b2,
                          const float* __restrict__ b3, const float* __restrict__ w4,
                          const float* __restrict__ w_self, const float* __restrict__ w_neigh,
                          u16* __restrict__ wcat, u16* __restrict__ wfin,
                          float* __restrict__ b1p, float* __restrict__ b2p,
                          float* __restrict__ b3p, float* __restrict__ w4p)
{
  const int idx = blockIdx.x * 256 + threadIdx.x;
  if (idx < 57344) {
    const float* w; int K, nsteps, loc;
    if (idx < 16384)      { loc = idx;         w = w1; K = 64;  nsteps = 2; }
    else if (idx < 49152) { loc = idx - 16384; w = w2; K = 256; nsteps = 8; }
    else                  { loc = idx - 49152; w = w3; K = 128; nsteps = 4; }
    const int chunk = loc >> 9;
    const int lane  = (loc >> 3) & 63;
    const int j     = loc & 7;
    const int t = chunk / nsteps, s = chunk % nsteps;
    const int m = sig(t * 16 + (lane & 15));
    const int k = s * 32 + (lane >> 4) * 8 + j;
    wcat[idx] = f2bf(w[m * K + k]);
  } else if (idx < 65536) {
    // wfin: [w_self | w_neigh] as 64x128, chunk c = t*4+s, NO permutation
    const int o = idx - 57344;
    const int c = o >> 9, lane = (o >> 3) & 63, j = o & 7;
    const int t = c >> 2, s = c & 3;
    const int m = 16 * t + (lane & 15);
    const int k = 32 * s + ((lane >> 4) << 3) + j;
    wfin[o] = f2bf(k < 64 ? w_self[m * 64 + k] : w_neigh[m * 64 + (k - 64)]);
  }
  if (idx < 256) b1p[idx] = b1[sig(idx)];
  if (idx < 128) b2p[idx] = b2[sig(idx)];
  if (idx < 64)  { b3p[idx] = b3[sig(idx)]; w4p[idx] = w4[sig(idx)]; }
}

extern "C" void kernel_launch(void* const* d_in, const int* in_sizes, int n_in,
                              void* d_out, int out_size, void* d_ws, size_t ws_size,
                              hipStream_t stream)
{
  const float* x       = (const float*)d_in[0];
  const int*   src     = (const int*)d_in[1];
  const int*   dst     = (const int*)d_in[2];
  const float* w1      = (const float*)d_in[3];
  const float* b1      = (const float*)d_in[4];
  const float* w2      = (const float*)d_in[5];
  const float* b2      = (const float*)d_in[6];
  const float* w3      = (const float*)d_in[7];
  const float* b3      = (const float*)d_in[8];
  const float* w4      = (const float*)d_in[9];
  const float* b4      = (const float*)d_in[10];
  const float* w_self  = (const float*)d_in[11];
  const float* w_neigh = (const float*)d_in[12];
  const float* bias    = (const float*)d_in[13];

  const int N = in_sizes[0] / 64;
  const int E = in_sizes[1];

  float* A    = (float*)d_out;                    // [N,64]
  float* eout = (float*)d_out + (size_t)N * 64;   // [E]

  char* ws = (char*)d_ws;
  size_t off = 0;
  auto alloc = [&](size_t bytes) {
    void* p = ws + off;
    off = (off + bytes + 255) & ~(size_t)255;
    return p;
  };
  int*    degi   = (int*)alloc((size_t)N * 4);
  int*    rowptr = (int*)alloc((size_t)(N + 1) * 4);
  int*    ord    = (int*)alloc((size_t)E * 4);
  int*    bsum   = (int*)alloc(1024 * 4);
  short8* wcat   = (short8*)alloc((size_t)57344 * 2);
  short8* wfin   = (short8*)alloc((size_t)8192 * 2);
  float*  b1p    = (float*)alloc(256 * 4);
  float*  b2p    = (float*)alloc(128 * 4);
  float*  b3p    = (float*)alloc(64 * 4);
  float*  w4p    = (float*)alloc(64 * 4);
  u16*    msgbuf = (u16*)alloc((size_t)E * 128);

  hipMemsetAsync(degi, 0, (size_t)N * sizeof(int), stream);

  convert_w<<<256, 256, 0, stream>>>(w1, w2, w3, b1, b2, b3, w4, w_self, w_neigh,
                                     (u16*)wcat, (u16*)wfin, b1p, b2p, b3p, w4p);

  deg_hist<<<(E + 255) / 256, 256, 0, stream>>>(dst, degi, ord, E);

  const int nsb = (N + 1023) / 1024;   // <= 256 for N <= 262144
  scan_part<<<nsb, 256, 0, stream>>>(degi, rowptr, bsum, N);
  scan_bsum<<<1, 256, 0, stream>>>(bsum, nsb);
  scan_add<<<nsb, 256, 0, stream>>>(rowptr, bsum, N, E);

  const int nblk = (E + 127) / 128;    // 128 edges per 256-thread block
  edge_mlp<<<nblk, 256, 0, stream>>>(x, src, dst, wcat, b1p, b2p, b3p, w4p, b4,
                                     rowptr, ord, msgbuf, eout, E);

  const int nblk2 = (N + 63) / 64;     // 64 nodes per 256-thread block
  node_agg_mfma<<<nblk2, 256, 0, stream>>>(x, msgbuf, rowptr, wfin, bias, A, N);
}